// Round 5
// baseline (1094.388 us; speedup 1.0000x reference)
//
#include <hip/hip_runtime.h>
#include <math.h>

#define NBUCKETS 65536
#define EPS 1e-12

typedef float v4f __attribute__((ext_vector_type(4)));
typedef int v4i __attribute__((ext_vector_type(4)));
typedef unsigned int v4u __attribute__((ext_vector_type(4)));

// ---------------- new path (LDS histogram, no global atomics) ----------------
#define NWG 256
#define WGT 1024
#define RROUNDS 8           // v4 loads per thread -> 32 items/thread
#define PASSES 2
#define PBUCK 32768         // buckets per pass (128 KB LDS -> 1 wg/CU)
#define SCALE_F 131072.0f   // 2^17 fixed point
#define INV_SCALE (1.0 / 131072.0)
#define SUM_MASK 0x0FFFFFFFu

// new ws layout
#define OFF_HIST 0                                         // 256*65536*4 = 64 MB
#define OFF_CS   (NWG * NBUCKETS * 4)                      // 67108864, 256 doubles
#define OFF_SX   (OFF_CS + 256 * 8)                        // 67110912, 256 floats
#define OFF_CTRL (OFF_SX + NWG * 4)                        // 67111936, 64 B control
#define REQ_NEW  (OFF_CTRL + 64)
// ctrl: [0]=phase1 counter, [1]=phase2 counter, [2..3]=nll_total (double), [4]=nev_total

// old (fallback) ws layout
#define NREP 8
#define OSCALE_F 1073741824.0f
#define OINV_SCALE (1.0 / 1073741824.0)
#define LOW48 ((1ull << 48) - 1)
#define O_REP 0
#define O_SD (NREP * NBUCKETS * 8)
#define O_M (O_SD + NBUCKETS * 8)
#define O_CS (O_M + NBUCKETS * 4)
#define O_NLL (O_CS + 256 * 8)
#define O_NEV (O_NLL + 256 * 8)
#define O_SX (O_NEV + 256 * 4)
#define REQ_OLD (O_SX + 8192 * 4)

__device__ __forceinline__ unsigned int xcd_id() {
    unsigned int x;
    asm volatile("s_getreg_b32 %0, hwreg(HW_REG_XCC_ID)" : "=s"(x));
    return x & 7u;
}

// ------------------------- scatter: registers -> LDS (2 passes) -> hist -------------------------
__global__ __launch_bounds__(WGT) void scatter_lds_kernel(
        const v4f* __restrict__ x4, const v4i* __restrict__ e4,
        const v4i* __restrict__ t4, unsigned int* __restrict__ hist,
        float* __restrict__ sum_ex_part, unsigned int* __restrict__ ctrl, int n4,
        const float* __restrict__ x_s, const int* __restrict__ e_s,
        const int* __restrict__ t_s, int tail_base, int tail_cnt) {
    __shared__ unsigned int lds[PBUCK];
    const int t = threadIdx.x;
    const int wg = blockIdx.x;

    // zero the control block for the fused tail kernel (kernel-boundary visibility)
    if (wg == 0 && t == 0) {
        ctrl[0] = 0u;
        ctrl[1] = 0u;
        ((double*)ctrl)[1] = 0.0;   // nll_total at bytes 8..15
        ctrl[4] = 0u;
    }

    unsigned int pk[RROUNDS * 4];
    unsigned int bk[RROUNDS * 4];
    float ev_x = 0.0f;

#pragma unroll
    for (int r = 0; r < RROUNDS; r++) {
        int idx = (wg * RROUNDS + r) * WGT + t;
        bool ok = idx < n4;
        v4f x = {0.0f, 0.0f, 0.0f, 0.0f};
        v4i e = {0, 0, 0, 0};
        v4i tm = {0, 0, 0, 0};
        if (ok) {
            x = __builtin_nontemporal_load(&x4[idx]);
            e = __builtin_nontemporal_load(&e4[idx]);
            tm = __builtin_nontemporal_load(&t4[idx]);
        }
#pragma unroll
        for (int k = 0; k < 4; k++) {
            int j = r * 4 + k;
            if (ok) {
                float xv = x[k];
                unsigned int ev = (e[k] != 0) ? 1u : 0u;
                pk[j] = (ev << 28) + (unsigned int)(expf(xv) * SCALE_F + 0.5f);
                bk[j] = (unsigned int)tm[k] & 0xFFFFu;
                if (ev) ev_x += xv;
            } else {
                pk[j] = 0u;
                bk[j] = 0u;
            }
        }
    }

    // N%4 tail: wg 0 / thread 0 stashes up to 3 scalar items
    unsigned int pkt[4], bkt[4];
    int my_tail = 0;
    if (wg == 0 && t == 0 && tail_cnt > 0) {
        my_tail = tail_cnt;
        for (int i = 0; i < tail_cnt; i++) {
            int idx = tail_base + i;
            float xv = x_s[idx];
            unsigned int ev = (e_s[idx] != 0) ? 1u : 0u;
            pkt[i] = (ev << 28) + (unsigned int)(expf(xv) * SCALE_F + 0.5f);
            bkt[i] = (unsigned int)t_s[idx] & 0xFFFFu;
            if (ev) ev_x += xv;
        }
    }

    v4u* lds4 = (v4u*)lds;
#pragma unroll 1
    for (int p = 0; p < PASSES; p++) {
#pragma unroll
        for (int q = 0; q < PBUCK / 4 / WGT; q++)
            lds4[t + q * WGT] = (v4u){0u, 0u, 0u, 0u};
        __syncthreads();

        unsigned int up = (unsigned int)p;
#pragma unroll
        for (int j = 0; j < RROUNDS * 4; j++) {
            if (pk[j] != 0u && (bk[j] >> 15) == up)
                atomicAdd(&lds[bk[j] & (PBUCK - 1)], pk[j]);
        }
        for (int i = 0; i < my_tail; i++) {
            if ((bkt[i] >> 15) == up)
                atomicAdd(&lds[bkt[i] & (PBUCK - 1)], pkt[i]);
        }
        __syncthreads();

        v4u* hbase = (v4u*)(hist + (size_t)wg * NBUCKETS + (size_t)p * PBUCK);
#pragma unroll
        for (int q = 0; q < PBUCK / 4 / WGT; q++) {
            v4u v = lds4[t + q * WGT];
            __builtin_nontemporal_store(v, &hbase[t + q * WGT]);
        }
        __syncthreads();
    }

    // wave-reduce ev_x, then cross-wave via LDS (barriered above)
#pragma unroll
    for (int off = 32; off > 0; off >>= 1) ev_x += __shfl_down(ev_x, off, 64);
    if ((t & 63) == 0) lds[t >> 6] = __float_as_uint(ev_x);
    __syncthreads();
    if (t == 0) {
        float s = 0.0f;
        for (int w = 0; w < WGT / 64; w++) s += __uint_as_float(lds[w]);
        sum_ex_part[wg] = s;
    }
}

// ----------------- fused merge + suffix + final (one launch, manual grid barrier) -----------------
// 256 blocks x 256 threads; block b owns buckets [b*256, b*256+256).
__global__ __launch_bounds__(256) void merge_suffix_final_kernel(
        const v4u* __restrict__ hist4, double* __restrict__ chunk_sum,
        const float* __restrict__ sum_ex_part, unsigned int* __restrict__ ctrl,
        float* __restrict__ out) {
    const int t = threadIdx.x, b = blockIdx.x;
    const int tg = t >> 6, lane = t & 63;

    // phase 1: reduce 256 wg-slabs. wave tg handles wgs [tg*64, tg*64+64),
    // reading v4u (16 B/lane, 1 KB/wave/instruction).
    unsigned long long s[4] = {0ull, 0ull, 0ull, 0ull};
    unsigned int c[4] = {0u, 0u, 0u, 0u};
    const v4u* base = hist4 + (size_t)(tg * 64) * (NBUCKETS / 4) + (size_t)b * 64 + lane;
#pragma unroll 4
    for (int w = 0; w < 64; w++) {
        v4u h = base[(size_t)w * (NBUCKETS / 4)];
#pragma unroll
        for (int q = 0; q < 4; q++) {
            s[q] += (unsigned long long)(h[q] & SUM_MASK);
            c[q] += h[q] >> 28;
        }
    }
    __shared__ unsigned long long lsum[4][64][4];
    __shared__ unsigned int lcnt[4][64][4];
#pragma unroll
    for (int q = 0; q < 4; q++) { lsum[tg][lane][q] = s[q]; lcnt[tg][lane][q] = c[q]; }
    __syncthreads();

    // bucket b*256 + t  <->  (lane2 = t>>2, comp = t&3)
    unsigned long long Ssum = lsum[0][t >> 2][t & 3] + lsum[1][t >> 2][t & 3] +
                              lsum[2][t >> 2][t & 3] + lsum[3][t >> 2][t & 3];
    unsigned int M = lcnt[0][t >> 2][t & 3] + lcnt[1][t >> 2][t & 3] +
                     lcnt[2][t >> 2][t & 3] + lcnt[3][t >> 2][t & 3];
    double sv = (double)Ssum * INV_SCALE;

    __shared__ double red[256];
    __shared__ double sfx[256];
    __shared__ unsigned int ured[256];
    __shared__ int lastblk;

    // chunk total -> publish -> grid barrier (device-scope, cross-XCD safe)
    red[t] = sv;
    __syncthreads();
    for (int st = 128; st > 0; st >>= 1) {
        if (t < st) red[t] += red[t + st];
        __syncthreads();
    }
    if (t == 0) {
        __hip_atomic_store(&chunk_sum[b], red[0], __ATOMIC_RELEASE,
                           __HIP_MEMORY_SCOPE_AGENT);
        __hip_atomic_fetch_add(&ctrl[0], 1u, __ATOMIC_ACQ_REL,
                               __HIP_MEMORY_SCOPE_AGENT);
        while (__hip_atomic_load(&ctrl[0], __ATOMIC_ACQUIRE,
                                 __HIP_MEMORY_SCOPE_AGENT) < (unsigned)gridDim.x)
            __builtin_amdgcn_s_sleep(8);
    }
    __syncthreads();

    // phase 2: cross-chunk offset (sum of chunk_sum[c] for c > b)
    double cst = __hip_atomic_load(&chunk_sum[t], __ATOMIC_RELAXED,
                                   __HIP_MEMORY_SCOPE_AGENT);
    red[t] = (t > b) ? cst : 0.0;
    __syncthreads();
    for (int st = 128; st > 0; st >>= 1) {
        if (t < st) red[t] += red[t + st];
        __syncthreads();
    }
    double offset = red[0];
    __syncthreads();

    // inclusive suffix scan within chunk
    sfx[t] = sv;
    __syncthreads();
    for (int st = 1; st < 256; st <<= 1) {
        double add = (t + st < 256) ? sfx[t + st] : 0.0;
        __syncthreads();
        sfx[t] += add;
        __syncthreads();
    }
    double denom = offset + sfx[t] + EPS;
    double nll = (M != 0u) ? (double)M * log(denom) : 0.0;

    // block reduce nll + event count, accumulate device-wide, last block finalizes
    red[t] = nll;
    ured[t] = M;
    __syncthreads();
    for (int st = 128; st > 0; st >>= 1) {
        if (t < st) { red[t] += red[t + st]; ured[t] += ured[t + st]; }
        __syncthreads();
    }
    if (t == 0) {
        atomicAdd((double*)ctrl + 1, red[0]);
        atomicAdd(&ctrl[4], ured[0]);
        __threadfence();
        unsigned int old = __hip_atomic_fetch_add(&ctrl[1], 1u, __ATOMIC_ACQ_REL,
                                                  __HIP_MEMORY_SCOPE_AGENT);
        lastblk = (old == (unsigned)gridDim.x - 1) ? 1 : 0;
    }
    __syncthreads();
    if (lastblk) {
        red[t] = (double)sum_ex_part[t];
        __syncthreads();
        for (int st = 128; st > 0; st >>= 1) {
            if (t < st) red[t] += red[t + st];
            __syncthreads();
        }
        if (t == 0) {
            double nllT = __hip_atomic_load((double*)ctrl + 1, __ATOMIC_RELAXED,
                                            __HIP_MEMORY_SCOPE_AGENT);
            unsigned int nev = __hip_atomic_load(&ctrl[4], __ATOMIC_RELAXED,
                                                 __HIP_MEMORY_SCOPE_AGENT);
            out[0] = (float)((nllT - red[0]) / ((double)nev + EPS));
        }
    }
}

// ------------------------- old (fallback) path kernels -------------------------
__global__ void zero_ws_kernel(unsigned long long* __restrict__ rep, int n) {
    int i = blockIdx.x * blockDim.x + threadIdx.x;
    if (i < n) rep[i] = 0ull;
}

__global__ __launch_bounds__(256) void scatter_atomic_kernel(
        const v4f* __restrict__ x4, const v4i* __restrict__ e4,
        const v4i* __restrict__ t4,
        unsigned long long* __restrict__ rep, float* __restrict__ sum_ex_part,
        int n4, const float* __restrict__ x_s, const int* __restrict__ e_s,
        const int* __restrict__ t_s, int tail_base, int tail_cnt) {
    int i = blockIdx.x * blockDim.x + threadIdx.x;
    unsigned long long* R = rep + (size_t)xcd_id() * NBUCKETS;
    float ev_x = 0.0f;
    if (i < n4) {
        v4f x = __builtin_nontemporal_load(&x4[i]);
        v4i e = __builtin_nontemporal_load(&e4[i]);
        v4i t = __builtin_nontemporal_load(&t4[i]);
#pragma unroll
        for (int k = 0; k < 4; k++) {
            float xv = x[k];
            unsigned int v = (unsigned int)t[k] & 0xFFFFu;
            unsigned long long pk =
                ((unsigned long long)(e[k] != 0) << 48) +
                (unsigned long long)(expf(xv) * OSCALE_F + 0.5f);
            __hip_atomic_fetch_add(&R[v], pk, __ATOMIC_RELAXED,
                                   __HIP_MEMORY_SCOPE_WORKGROUP);
            if (e[k]) ev_x += xv;
        }
    }
    if (i < tail_cnt) {
        int idx = tail_base + i;
        float xv = x_s[idx];
        unsigned int v = (unsigned int)t_s[idx] & 0xFFFFu;
        unsigned long long pk =
            ((unsigned long long)(e_s[idx] != 0) << 48) +
            (unsigned long long)(expf(xv) * OSCALE_F + 0.5f);
        __hip_atomic_fetch_add(&R[v], pk, __ATOMIC_RELAXED,
                               __HIP_MEMORY_SCOPE_WORKGROUP);
        if (e_s[idx]) ev_x += xv;
    }
    __shared__ float sred[256];
    sred[threadIdx.x] = ev_x;
    __syncthreads();
    for (int s = 128; s > 0; s >>= 1) {
        if ((int)threadIdx.x < s) sred[threadIdx.x] += sred[threadIdx.x + s];
        __syncthreads();
    }
    if (threadIdx.x == 0) sum_ex_part[blockIdx.x] = sred[0];
}

__global__ __launch_bounds__(256) void reduce_kernel(
        const unsigned long long* __restrict__ rep, double* __restrict__ Sd,
        unsigned int* __restrict__ m, double* __restrict__ chunk_sum) {
    int t = threadIdx.x;
    int i = blockIdx.x * 256 + t;
    unsigned long long acc = 0ull;
#pragma unroll
    for (int r = 0; r < NREP; r++) acc += rep[(size_t)r * NBUCKETS + i];
    double sv = (double)(acc & LOW48) * OINV_SCALE;
    unsigned int mv = (unsigned int)(acc >> 48);
    Sd[i] = sv;
    m[i] = mv;
    __shared__ double red[256];
    red[t] = sv;
    __syncthreads();
    for (int s = 128; s > 0; s >>= 1) {
        if (t < s) red[t] += red[t + s];
        __syncthreads();
    }
    if (t == 0) chunk_sum[blockIdx.x] = red[0];
}

__global__ __launch_bounds__(256) void suffix_kernel(
        const double* __restrict__ Sd, const unsigned int* __restrict__ m,
        const double* __restrict__ chunk_sum, double* __restrict__ nll_part,
        unsigned int* __restrict__ nev_part) {
    __shared__ double cs[256];
    __shared__ double sfx[256];
    __shared__ unsigned int ured[256];
    const int t = threadIdx.x;
    const int b = blockIdx.x;

    cs[t] = (t > b) ? chunk_sum[t] : 0.0;
    __syncthreads();
    for (int s = 128; s > 0; s >>= 1) {
        if (t < s) cs[t] += cs[t + s];
        __syncthreads();
    }
    double offset = cs[0];
    __syncthreads();

    int i = b * 256 + t;
    double sv = Sd[i];
    unsigned int mv = m[i];

    sfx[t] = sv;
    __syncthreads();
    for (int s = 1; s < 256; s <<= 1) {
        double add = (t + s < 256) ? sfx[t + s] : 0.0;
        __syncthreads();
        sfx[t] += add;
        __syncthreads();
    }

    double denom = offset + sfx[t] + EPS;
    double nll = (mv != 0u) ? (double)mv * log(denom) : 0.0;

    cs[t] = nll;
    ured[t] = mv;
    __syncthreads();
    for (int s = 128; s > 0; s >>= 1) {
        if (t < s) { cs[t] += cs[t + s]; ured[t] += ured[t + s]; }
        __syncthreads();
    }
    if (t == 0) {
        nll_part[b] = cs[0];
        nev_part[b] = ured[0];
    }
}

__global__ __launch_bounds__(256) void final_kernel(
        const double* __restrict__ nll_part, const unsigned int* __restrict__ nev_part,
        const float* __restrict__ sum_ex_part, int n_sx, float* __restrict__ out) {
    __shared__ double rd[256];
    __shared__ double rs[256];
    __shared__ unsigned int ru[256];
    int t = threadIdx.x;
    double nll = nll_part[t];
    unsigned int ne = nev_part[t];
    double sx = 0.0;
    for (int i = t; i < n_sx; i += 256) sx += (double)sum_ex_part[i];
    rd[t] = nll;
    rs[t] = sx;
    ru[t] = ne;
    __syncthreads();
    for (int s = 128; s > 0; s >>= 1) {
        if (t < s) { rd[t] += rd[t + s]; rs[t] += rs[t + s]; ru[t] += ru[t + s]; }
        __syncthreads();
    }
    if (t == 0) {
        double total = rd[0] - rs[0];
        out[0] = (float)(total / ((double)ru[0] + EPS));
    }
}

extern "C" void kernel_launch(void* const* d_in, const int* in_sizes, int n_in,
                              void* d_out, int out_size, void* d_ws, size_t ws_size,
                              hipStream_t stream) {
    const float* logits = (const float*)d_in[0];
    const int* status = (const int*)d_in[1];
    const int* time = (const int*)d_in[2];
    const int N = in_sizes[0];

    char* ws = (char*)d_ws;
    int n4 = N / 4;
    int tail_base = n4 * 4;
    int tail_cnt = N - tail_base;

    if (ws_size >= (size_t)REQ_NEW && N <= NWG * WGT * RROUNDS * 4) {
        unsigned int* hist = (unsigned int*)(ws + OFF_HIST);
        double* chunk_sum = (double*)(ws + OFF_CS);
        float* sum_ex_part = (float*)(ws + OFF_SX);
        unsigned int* ctrl = (unsigned int*)(ws + OFF_CTRL);

        scatter_lds_kernel<<<NWG, WGT, 0, stream>>>(
            (const v4f*)logits, (const v4i*)status, (const v4i*)time,
            hist, sum_ex_part, ctrl, n4, logits, status, time, tail_base, tail_cnt);
        merge_suffix_final_kernel<<<256, 256, 0, stream>>>(
            (const v4u*)hist, chunk_sum, sum_ex_part, ctrl, (float*)d_out);
    } else {
        unsigned long long* rep = (unsigned long long*)(ws + O_REP);
        double* Sd = (double*)(ws + O_SD);
        unsigned int* m = (unsigned int*)(ws + O_M);
        double* chunk_sum = (double*)(ws + O_CS);
        double* nll_part = (double*)(ws + O_NLL);
        unsigned int* nev_part = (unsigned int*)(ws + O_NEV);
        float* sum_ex_part = (float*)(ws + O_SX);

        int nrep_total = NREP * NBUCKETS;
        zero_ws_kernel<<<(nrep_total + 255) / 256, 256, 0, stream>>>(rep, nrep_total);
        int blocks = (n4 + 255) / 256;
        if (blocks < 1) blocks = 1;
        scatter_atomic_kernel<<<blocks, 256, 0, stream>>>(
            (const v4f*)logits, (const v4i*)status, (const v4i*)time,
            rep, sum_ex_part, n4, logits, status, time, tail_base, tail_cnt);
        reduce_kernel<<<256, 256, 0, stream>>>(rep, Sd, m, chunk_sum);
        suffix_kernel<<<256, 256, 0, stream>>>(Sd, m, chunk_sum, nll_part, nev_part);
        final_kernel<<<1, 256, 0, stream>>>(nll_part, nev_part, sum_ex_part, blocks,
                                            (float*)d_out);
    }
}

// Round 6
// 1089.961 us; speedup vs baseline: 1.0041x; 1.0041x over previous
//
#include <hip/hip_runtime.h>
#include <math.h>

#define NBUCKETS 65536
#define EPS 1e-12

typedef float v4f __attribute__((ext_vector_type(4)));
typedef int v4i __attribute__((ext_vector_type(4)));
typedef unsigned int v4u __attribute__((ext_vector_type(4)));

// ---------------- new path (LDS histogram, no global atomics) ----------------
#define NWG 256
#define WGT 1024
#define RROUNDS 8           // v4 loads per thread -> 32 items/thread
#define PASSES 2
#define PBUCK 32768         // buckets per pass (128 KB LDS -> 1 wg/CU)
#define SCALE_F 131072.0f   // 2^17 fixed point
#define INV_SCALE (1.0 / 131072.0)
#define SUM_MASK 0x0FFFFFFFu

// new ws layout
#define OFF_HIST 0                                         // 256*65536*4 = 64 MB
#define OFF_CS   (NWG * NBUCKETS * 4)                      // 67108864, 256 doubles
#define OFF_SX   (OFF_CS + 256 * 8)                        // 67110912, 256 floats
#define OFF_CTRL (OFF_SX + NWG * 4)                        // 67111936, 64 B control
#define REQ_NEW  (OFF_CTRL + 64)
// ctrl: [0]=phase1 counter, [1]=phase2 counter, [2..3]=nll_total (double), [4]=nev_total

// old (fallback) ws layout
#define NREP 8
#define OSCALE_F 1073741824.0f
#define OINV_SCALE (1.0 / 1073741824.0)
#define LOW48 ((1ull << 48) - 1)
#define O_REP 0
#define O_SD (NREP * NBUCKETS * 8)
#define O_M (O_SD + NBUCKETS * 8)
#define O_CS (O_M + NBUCKETS * 4)
#define O_NLL (O_CS + 256 * 8)
#define O_NEV (O_NLL + 256 * 8)
#define O_SX (O_NEV + 256 * 4)
#define REQ_OLD (O_SX + 8192 * 4)

__device__ __forceinline__ unsigned int xcd_id() {
    unsigned int x;
    asm volatile("s_getreg_b32 %0, hwreg(HW_REG_XCC_ID)" : "=s"(x));
    return x & 7u;
}

// ------------------------- scatter: registers -> LDS (2 passes) -> hist -------------------------
// __launch_bounds__(1024, 4): min 4 waves/EU => 128-VGPR budget. DO NOT drop the
// ",4": without it the compiler caps at 64 VGPRs (targeting 8 waves/EU that the
// 128 KB LDS can never host) and spills the 64-reg pk/bk stash to scratch
// (round-5 counters: VGPR=64, 3.4 GB of scratch traffic, 25x slowdown).
__global__ __launch_bounds__(WGT, 4) void scatter_lds_kernel(
        const v4f* __restrict__ x4, const v4i* __restrict__ e4,
        const v4i* __restrict__ t4, unsigned int* __restrict__ hist,
        float* __restrict__ sum_ex_part, unsigned int* __restrict__ ctrl, int n4,
        const float* __restrict__ x_s, const int* __restrict__ e_s,
        const int* __restrict__ t_s, int tail_base, int tail_cnt) {
    __shared__ unsigned int lds[PBUCK];
    const int t = threadIdx.x;
    const int wg = blockIdx.x;

    // zero the control block for the fused tail kernel (kernel-boundary visibility)
    if (wg == 0 && t == 0) {
        ctrl[0] = 0u;
        ctrl[1] = 0u;
        ((double*)ctrl)[1] = 0.0;   // nll_total at bytes 8..15
        ctrl[4] = 0u;
    }

    unsigned int pk[RROUNDS * 4];
    unsigned int bk[RROUNDS * 4];
    float ev_x = 0.0f;

#pragma unroll
    for (int r = 0; r < RROUNDS; r++) {
        int idx = (wg * RROUNDS + r) * WGT + t;
        bool ok = idx < n4;
        v4f x = {0.0f, 0.0f, 0.0f, 0.0f};
        v4i e = {0, 0, 0, 0};
        v4i tm = {0, 0, 0, 0};
        if (ok) {
            x = __builtin_nontemporal_load(&x4[idx]);
            e = __builtin_nontemporal_load(&e4[idx]);
            tm = __builtin_nontemporal_load(&t4[idx]);
        }
#pragma unroll
        for (int k = 0; k < 4; k++) {
            int j = r * 4 + k;
            if (ok) {
                float xv = x[k];
                unsigned int ev = (e[k] != 0) ? 1u : 0u;
                pk[j] = (ev << 28) + (unsigned int)(expf(xv) * SCALE_F + 0.5f);
                bk[j] = (unsigned int)tm[k] & 0xFFFFu;
                if (ev) ev_x += xv;
            } else {
                pk[j] = 0u;
                bk[j] = 0u;
            }
        }
    }

    // N%4 tail: wg 0 / thread 0 stashes up to 3 scalar items
    unsigned int pkt[4], bkt[4];
    int my_tail = 0;
    if (wg == 0 && t == 0 && tail_cnt > 0) {
        my_tail = tail_cnt;
        for (int i = 0; i < tail_cnt; i++) {
            int idx = tail_base + i;
            float xv = x_s[idx];
            unsigned int ev = (e_s[idx] != 0) ? 1u : 0u;
            pkt[i] = (ev << 28) + (unsigned int)(expf(xv) * SCALE_F + 0.5f);
            bkt[i] = (unsigned int)t_s[idx] & 0xFFFFu;
            if (ev) ev_x += xv;
        }
    }

    v4u* lds4 = (v4u*)lds;
#pragma unroll 1
    for (int p = 0; p < PASSES; p++) {
#pragma unroll
        for (int q = 0; q < PBUCK / 4 / WGT; q++)
            lds4[t + q * WGT] = (v4u){0u, 0u, 0u, 0u};
        __syncthreads();

        unsigned int up = (unsigned int)p;
#pragma unroll
        for (int j = 0; j < RROUNDS * 4; j++) {
            if (pk[j] != 0u && (bk[j] >> 15) == up)
                atomicAdd(&lds[bk[j] & (PBUCK - 1)], pk[j]);
        }
        for (int i = 0; i < my_tail; i++) {
            if ((bkt[i] >> 15) == up)
                atomicAdd(&lds[bkt[i] & (PBUCK - 1)], pkt[i]);
        }
        __syncthreads();

        v4u* hbase = (v4u*)(hist + (size_t)wg * NBUCKETS + (size_t)p * PBUCK);
#pragma unroll
        for (int q = 0; q < PBUCK / 4 / WGT; q++) {
            v4u v = lds4[t + q * WGT];
            __builtin_nontemporal_store(v, &hbase[t + q * WGT]);
        }
        __syncthreads();
    }

    // wave-reduce ev_x, then cross-wave via LDS (barriered above)
#pragma unroll
    for (int off = 32; off > 0; off >>= 1) ev_x += __shfl_down(ev_x, off, 64);
    if ((t & 63) == 0) lds[t >> 6] = __float_as_uint(ev_x);
    __syncthreads();
    if (t == 0) {
        float s = 0.0f;
        for (int w = 0; w < WGT / 64; w++) s += __uint_as_float(lds[w]);
        sum_ex_part[wg] = s;
    }
}

// ----------------- fused merge + suffix + final (one launch, manual grid barrier) -----------------
// 256 blocks x 256 threads; block b owns buckets [b*256, b*256+256).
__global__ __launch_bounds__(256) void merge_suffix_final_kernel(
        const v4u* __restrict__ hist4, double* __restrict__ chunk_sum,
        const float* __restrict__ sum_ex_part, unsigned int* __restrict__ ctrl,
        float* __restrict__ out) {
    const int t = threadIdx.x, b = blockIdx.x;
    const int tg = t >> 6, lane = t & 63;

    // phase 1: reduce 256 wg-slabs. wave tg handles wgs [tg*64, tg*64+64),
    // reading v4u (16 B/lane, 1 KB/wave/instruction).
    unsigned long long s[4] = {0ull, 0ull, 0ull, 0ull};
    unsigned int c[4] = {0u, 0u, 0u, 0u};
    const v4u* base = hist4 + (size_t)(tg * 64) * (NBUCKETS / 4) + (size_t)b * 64 + lane;
#pragma unroll 4
    for (int w = 0; w < 64; w++) {
        v4u h = base[(size_t)w * (NBUCKETS / 4)];
#pragma unroll
        for (int q = 0; q < 4; q++) {
            s[q] += (unsigned long long)(h[q] & SUM_MASK);
            c[q] += h[q] >> 28;
        }
    }
    __shared__ unsigned long long lsum[4][64][4];
    __shared__ unsigned int lcnt[4][64][4];
#pragma unroll
    for (int q = 0; q < 4; q++) { lsum[tg][lane][q] = s[q]; lcnt[tg][lane][q] = c[q]; }
    __syncthreads();

    // bucket b*256 + t  <->  (lane2 = t>>2, comp = t&3)
    unsigned long long Ssum = lsum[0][t >> 2][t & 3] + lsum[1][t >> 2][t & 3] +
                              lsum[2][t >> 2][t & 3] + lsum[3][t >> 2][t & 3];
    unsigned int M = lcnt[0][t >> 2][t & 3] + lcnt[1][t >> 2][t & 3] +
                     lcnt[2][t >> 2][t & 3] + lcnt[3][t >> 2][t & 3];
    double sv = (double)Ssum * INV_SCALE;

    __shared__ double red[256];
    __shared__ double sfx[256];
    __shared__ unsigned int ured[256];
    __shared__ int lastblk;

    // chunk total -> publish -> grid barrier (device-scope, cross-XCD safe)
    red[t] = sv;
    __syncthreads();
    for (int st = 128; st > 0; st >>= 1) {
        if (t < st) red[t] += red[t + st];
        __syncthreads();
    }
    if (t == 0) {
        __hip_atomic_store(&chunk_sum[b], red[0], __ATOMIC_RELEASE,
                           __HIP_MEMORY_SCOPE_AGENT);
        __hip_atomic_fetch_add(&ctrl[0], 1u, __ATOMIC_ACQ_REL,
                               __HIP_MEMORY_SCOPE_AGENT);
        while (__hip_atomic_load(&ctrl[0], __ATOMIC_ACQUIRE,
                                 __HIP_MEMORY_SCOPE_AGENT) < (unsigned)gridDim.x)
            __builtin_amdgcn_s_sleep(8);
    }
    __syncthreads();

    // phase 2: cross-chunk offset (sum of chunk_sum[c] for c > b)
    double cst = __hip_atomic_load(&chunk_sum[t], __ATOMIC_RELAXED,
                                   __HIP_MEMORY_SCOPE_AGENT);
    red[t] = (t > b) ? cst : 0.0;
    __syncthreads();
    for (int st = 128; st > 0; st >>= 1) {
        if (t < st) red[t] += red[t + st];
        __syncthreads();
    }
    double offset = red[0];
    __syncthreads();

    // inclusive suffix scan within chunk
    sfx[t] = sv;
    __syncthreads();
    for (int st = 1; st < 256; st <<= 1) {
        double add = (t + st < 256) ? sfx[t + st] : 0.0;
        __syncthreads();
        sfx[t] += add;
        __syncthreads();
    }
    double denom = offset + sfx[t] + EPS;
    double nll = (M != 0u) ? (double)M * log(denom) : 0.0;

    // block reduce nll + event count, accumulate device-wide, last block finalizes
    red[t] = nll;
    ured[t] = M;
    __syncthreads();
    for (int st = 128; st > 0; st >>= 1) {
        if (t < st) { red[t] += red[t + st]; ured[t] += ured[t + st]; }
        __syncthreads();
    }
    if (t == 0) {
        atomicAdd((double*)ctrl + 1, red[0]);
        atomicAdd(&ctrl[4], ured[0]);
        __threadfence();
        unsigned int old = __hip_atomic_fetch_add(&ctrl[1], 1u, __ATOMIC_ACQ_REL,
                                                  __HIP_MEMORY_SCOPE_AGENT);
        lastblk = (old == (unsigned)gridDim.x - 1) ? 1 : 0;
    }
    __syncthreads();
    if (lastblk) {
        red[t] = (double)sum_ex_part[t];
        __syncthreads();
        for (int st = 128; st > 0; st >>= 1) {
            if (t < st) red[t] += red[t + st];
            __syncthreads();
        }
        if (t == 0) {
            double nllT = __hip_atomic_load((double*)ctrl + 1, __ATOMIC_RELAXED,
                                            __HIP_MEMORY_SCOPE_AGENT);
            unsigned int nev = __hip_atomic_load(&ctrl[4], __ATOMIC_RELAXED,
                                                 __HIP_MEMORY_SCOPE_AGENT);
            out[0] = (float)((nllT - red[0]) / ((double)nev + EPS));
        }
    }
}

// ------------------------- old (fallback) path kernels -------------------------
__global__ void zero_ws_kernel(unsigned long long* __restrict__ rep, int n) {
    int i = blockIdx.x * blockDim.x + threadIdx.x;
    if (i < n) rep[i] = 0ull;
}

__global__ __launch_bounds__(256) void scatter_atomic_kernel(
        const v4f* __restrict__ x4, const v4i* __restrict__ e4,
        const v4i* __restrict__ t4,
        unsigned long long* __restrict__ rep, float* __restrict__ sum_ex_part,
        int n4, const float* __restrict__ x_s, const int* __restrict__ e_s,
        const int* __restrict__ t_s, int tail_base, int tail_cnt) {
    int i = blockIdx.x * blockDim.x + threadIdx.x;
    unsigned long long* R = rep + (size_t)xcd_id() * NBUCKETS;
    float ev_x = 0.0f;
    if (i < n4) {
        v4f x = __builtin_nontemporal_load(&x4[i]);
        v4i e = __builtin_nontemporal_load(&e4[i]);
        v4i t = __builtin_nontemporal_load(&t4[i]);
#pragma unroll
        for (int k = 0; k < 4; k++) {
            float xv = x[k];
            unsigned int v = (unsigned int)t[k] & 0xFFFFu;
            unsigned long long pk =
                ((unsigned long long)(e[k] != 0) << 48) +
                (unsigned long long)(expf(xv) * OSCALE_F + 0.5f);
            __hip_atomic_fetch_add(&R[v], pk, __ATOMIC_RELAXED,
                                   __HIP_MEMORY_SCOPE_WORKGROUP);
            if (e[k]) ev_x += xv;
        }
    }
    if (i < tail_cnt) {
        int idx = tail_base + i;
        float xv = x_s[idx];
        unsigned int v = (unsigned int)t_s[idx] & 0xFFFFu;
        unsigned long long pk =
            ((unsigned long long)(e_s[idx] != 0) << 48) +
            (unsigned long long)(expf(xv) * OSCALE_F + 0.5f);
        __hip_atomic_fetch_add(&R[v], pk, __ATOMIC_RELAXED,
                               __HIP_MEMORY_SCOPE_WORKGROUP);
        if (e_s[idx]) ev_x += xv;
    }
    __shared__ float sred[256];
    sred[threadIdx.x] = ev_x;
    __syncthreads();
    for (int s = 128; s > 0; s >>= 1) {
        if ((int)threadIdx.x < s) sred[threadIdx.x] += sred[threadIdx.x + s];
        __syncthreads();
    }
    if (threadIdx.x == 0) sum_ex_part[blockIdx.x] = sred[0];
}

__global__ __launch_bounds__(256) void reduce_kernel(
        const unsigned long long* __restrict__ rep, double* __restrict__ Sd,
        unsigned int* __restrict__ m, double* __restrict__ chunk_sum) {
    int t = threadIdx.x;
    int i = blockIdx.x * 256 + t;
    unsigned long long acc = 0ull;
#pragma unroll
    for (int r = 0; r < NREP; r++) acc += rep[(size_t)r * NBUCKETS + i];
    double sv = (double)(acc & LOW48) * OINV_SCALE;
    unsigned int mv = (unsigned int)(acc >> 48);
    Sd[i] = sv;
    m[i] = mv;
    __shared__ double red[256];
    red[t] = sv;
    __syncthreads();
    for (int s = 128; s > 0; s >>= 1) {
        if (t < s) red[t] += red[t + s];
        __syncthreads();
    }
    if (t == 0) chunk_sum[blockIdx.x] = red[0];
}

__global__ __launch_bounds__(256) void suffix_kernel(
        const double* __restrict__ Sd, const unsigned int* __restrict__ m,
        const double* __restrict__ chunk_sum, double* __restrict__ nll_part,
        unsigned int* __restrict__ nev_part) {
    __shared__ double cs[256];
    __shared__ double sfx[256];
    __shared__ unsigned int ured[256];
    const int t = threadIdx.x;
    const int b = blockIdx.x;

    cs[t] = (t > b) ? chunk_sum[t] : 0.0;
    __syncthreads();
    for (int s = 128; s > 0; s >>= 1) {
        if (t < s) cs[t] += cs[t + s];
        __syncthreads();
    }
    double offset = cs[0];
    __syncthreads();

    int i = b * 256 + t;
    double sv = Sd[i];
    unsigned int mv = m[i];

    sfx[t] = sv;
    __syncthreads();
    for (int s = 1; s < 256; s <<= 1) {
        double add = (t + s < 256) ? sfx[t + s] : 0.0;
        __syncthreads();
        sfx[t] += add;
        __syncthreads();
    }

    double denom = offset + sfx[t] + EPS;
    double nll = (mv != 0u) ? (double)mv * log(denom) : 0.0;

    cs[t] = nll;
    ured[t] = mv;
    __syncthreads();
    for (int s = 128; s > 0; s >>= 1) {
        if (t < s) { cs[t] += cs[t + s]; ured[t] += ured[t + s]; }
        __syncthreads();
    }
    if (t == 0) {
        nll_part[b] = cs[0];
        nev_part[b] = ured[0];
    }
}

__global__ __launch_bounds__(256) void final_kernel(
        const double* __restrict__ nll_part, const unsigned int* __restrict__ nev_part,
        const float* __restrict__ sum_ex_part, int n_sx, float* __restrict__ out) {
    __shared__ double rd[256];
    __shared__ double rs[256];
    __shared__ unsigned int ru[256];
    int t = threadIdx.x;
    double nll = nll_part[t];
    unsigned int ne = nev_part[t];
    double sx = 0.0;
    for (int i = t; i < n_sx; i += 256) sx += (double)sum_ex_part[i];
    rd[t] = nll;
    rs[t] = sx;
    ru[t] = ne;
    __syncthreads();
    for (int s = 128; s > 0; s >>= 1) {
        if (t < s) { rd[t] += rd[t + s]; rs[t] += rs[t + s]; ru[t] += ru[t + s]; }
        __syncthreads();
    }
    if (t == 0) {
        double total = rd[0] - rs[0];
        out[0] = (float)(total / ((double)ru[0] + EPS));
    }
}

extern "C" void kernel_launch(void* const* d_in, const int* in_sizes, int n_in,
                              void* d_out, int out_size, void* d_ws, size_t ws_size,
                              hipStream_t stream) {
    const float* logits = (const float*)d_in[0];
    const int* status = (const int*)d_in[1];
    const int* time = (const int*)d_in[2];
    const int N = in_sizes[0];

    char* ws = (char*)d_ws;
    int n4 = N / 4;
    int tail_base = n4 * 4;
    int tail_cnt = N - tail_base;

    if (ws_size >= (size_t)REQ_NEW && N <= NWG * WGT * RROUNDS * 4) {
        unsigned int* hist = (unsigned int*)(ws + OFF_HIST);
        double* chunk_sum = (double*)(ws + OFF_CS);
        float* sum_ex_part = (float*)(ws + OFF_SX);
        unsigned int* ctrl = (unsigned int*)(ws + OFF_CTRL);

        scatter_lds_kernel<<<NWG, WGT, 0, stream>>>(
            (const v4f*)logits, (const v4i*)status, (const v4i*)time,
            hist, sum_ex_part, ctrl, n4, logits, status, time, tail_base, tail_cnt);
        merge_suffix_final_kernel<<<256, 256, 0, stream>>>(
            (const v4u*)hist, chunk_sum, sum_ex_part, ctrl, (float*)d_out);
    } else {
        unsigned long long* rep = (unsigned long long*)(ws + O_REP);
        double* Sd = (double*)(ws + O_SD);
        unsigned int* m = (unsigned int*)(ws + O_M);
        double* chunk_sum = (double*)(ws + O_CS);
        double* nll_part = (double*)(ws + O_NLL);
        unsigned int* nev_part = (unsigned int*)(ws + O_NEV);
        float* sum_ex_part = (float*)(ws + O_SX);

        int nrep_total = NREP * NBUCKETS;
        zero_ws_kernel<<<(nrep_total + 255) / 256, 256, 0, stream>>>(rep, nrep_total);
        int blocks = (n4 + 255) / 256;
        if (blocks < 1) blocks = 1;
        scatter_atomic_kernel<<<blocks, 256, 0, stream>>>(
            (const v4f*)logits, (const v4i*)status, (const v4i*)time,
            rep, sum_ex_part, n4, logits, status, time, tail_base, tail_cnt);
        reduce_kernel<<<256, 256, 0, stream>>>(rep, Sd, m, chunk_sum);
        suffix_kernel<<<256, 256, 0, stream>>>(Sd, m, chunk_sum, nll_part, nev_part);
        final_kernel<<<1, 256, 0, stream>>>(nll_part, nev_part, sum_ex_part, blocks,
                                            (float*)d_out);
    }
}

// Round 7
// 188.179 us; speedup vs baseline: 5.8157x; 5.7922x over previous
//
#include <hip/hip_runtime.h>
#include <math.h>

#define NBUCKETS 65536
#define EPS 1e-12

typedef float v4f __attribute__((ext_vector_type(4)));
typedef int v4i __attribute__((ext_vector_type(4)));
typedef unsigned int v4u __attribute__((ext_vector_type(4)));

// ---------------- main path (LDS histogram, no global atomics, no reg stash) ----------------
#define NWG 256             // chunks
#define WGT 1024
#define RROUNDS 8           // v4 loads per thread -> 32 items/thread/chunk
#define PBUCK 32768         // buckets per half (128 KB LDS -> 1 wg/CU)
#define SCALE_F 131072.0f   // 2^17 fixed point
#define INV_SCALE (1.0 / 131072.0)
#define SUM_MASK 0x0FFFFFFFu

// ws layout
#define OFF_HIST 0                                         // 256*65536*4 = 64 MB
#define OFF_CS   (NWG * NBUCKETS * 4)                      // 67108864, 256 doubles
#define OFF_SX   (OFF_CS + 256 * 8)                        // 67110912, 256 floats
#define OFF_CTRL (OFF_SX + NWG * 4)                        // 67111936, 64 B control
#define REQ_NEW  (OFF_CTRL + 64)
// ctrl: [0]=phase1 counter, [1]=phase2 counter, [2..3]=nll_total (double), [4]=nev_total

// old (fallback) ws layout
#define NREP 8
#define OSCALE_F 1073741824.0f
#define OINV_SCALE (1.0 / 1073741824.0)
#define LOW48 ((1ull << 48) - 1)
#define O_REP 0
#define O_SD (NREP * NBUCKETS * 8)
#define O_M (O_SD + NBUCKETS * 8)
#define O_CS (O_M + NBUCKETS * 4)
#define O_NLL (O_CS + 256 * 8)
#define O_NEV (O_NLL + 256 * 8)
#define O_SX (O_NEV + 256 * 4)
#define REQ_OLD (O_SX + 8192 * 4)

__device__ __forceinline__ unsigned int xcd_id() {
    unsigned int x;
    asm volatile("s_getreg_b32 %0, hwreg(HW_REG_XCC_ID)" : "=s"(x));
    return x & 7u;
}

// ------------- scatter: 512 wgs = (chunk, bucket-half); stream -> LDS atomics -> slab -------------
// NO per-item register stash: rounds 5/6 showed the allocator pins VGPR=64 and
// spills a 64-reg stash to scratch (1.5 GB fetch, 25x slowdown) regardless of
// __launch_bounds__ hints. Each wg instead re-reads its chunk (2nd read is
// L3-resident) and filters to its bucket half. ~40 VGPRs live -> spill-proof.
__global__ __launch_bounds__(WGT) void scatter_half_kernel(
        const v4f* __restrict__ x4, const v4i* __restrict__ e4,
        const v4i* __restrict__ t4, unsigned int* __restrict__ hist,
        float* __restrict__ sum_ex_part, unsigned int* __restrict__ ctrl, int n4,
        const float* __restrict__ x_s, const int* __restrict__ e_s,
        const int* __restrict__ t_s, int tail_base, int tail_cnt) {
    __shared__ unsigned int lds[PBUCK];
    const int t = threadIdx.x;
    const int wg = blockIdx.x;
    const int half = wg & 1;
    const int chunk = wg >> 1;

    // zero the control block for the fused tail kernel (kernel-boundary visibility)
    if (wg == 0 && t == 0) {
        ctrl[0] = 0u;
        ctrl[1] = 0u;
        ((double*)ctrl)[1] = 0.0;   // nll_total at bytes 8..15
        ctrl[4] = 0u;
    }

    // zero the LDS histogram
    v4u* lds4 = (v4u*)lds;
#pragma unroll
    for (int q = 0; q < PBUCK / 4 / WGT; q++)
        lds4[t + q * WGT] = (v4u){0u, 0u, 0u, 0u};
    __syncthreads();

    float ev_x = 0.0f;
    const unsigned int uh = (unsigned int)half;

#pragma unroll
    for (int r = 0; r < RROUNDS; r++) {
        int idx = (chunk * RROUNDS + r) * WGT + t;
        if (idx < n4) {
            v4f x = __builtin_nontemporal_load(&x4[idx]);
            v4i e = __builtin_nontemporal_load(&e4[idx]);
            v4i tm = __builtin_nontemporal_load(&t4[idx]);
#pragma unroll
            for (int k = 0; k < 4; k++) {
                float xv = x[k];
                unsigned int b = (unsigned int)tm[k] & 0xFFFFu;
                unsigned int ev = (e[k] != 0) ? 1u : 0u;
                if ((b >> 15) == uh) {
                    unsigned int pk = (ev << 28) +
                                      (unsigned int)(expf(xv) * SCALE_F + 0.5f);
                    atomicAdd(&lds[b & (PBUCK - 1)], pk);
                }
                if (half == 0 && ev) ev_x += xv;  // sum_ex counted once (half 0)
            }
        }
    }

    // N%4 tail: both halves of chunk 0 check it (each keeps matching buckets)
    if (chunk == 0 && t == 0 && tail_cnt > 0) {
        for (int i = 0; i < tail_cnt; i++) {
            int idx = tail_base + i;
            float xv = x_s[idx];
            unsigned int b = (unsigned int)t_s[idx] & 0xFFFFu;
            unsigned int ev = (e_s[idx] != 0) ? 1u : 0u;
            if ((b >> 15) == uh) {
                unsigned int pk = (ev << 28) +
                                  (unsigned int)(expf(xv) * SCALE_F + 0.5f);
                atomicAdd(&lds[b & (PBUCK - 1)], pk);
            }
            if (half == 0 && ev) ev_x += xv;
        }
    }
    __syncthreads();

    // coalesced write-out of this half's 32K-bucket slab
    v4u* hbase = (v4u*)(hist + (size_t)chunk * NBUCKETS + (size_t)half * PBUCK);
#pragma unroll
    for (int q = 0; q < PBUCK / 4 / WGT; q++) {
        v4u v = lds4[t + q * WGT];
        __builtin_nontemporal_store(v, &hbase[t + q * WGT]);
    }

    // sum_ex partial (half 0 only): wave reduce, then cross-wave via LDS
    if (half == 0) {
        __syncthreads();
#pragma unroll
        for (int off = 32; off > 0; off >>= 1) ev_x += __shfl_down(ev_x, off, 64);
        if ((t & 63) == 0) lds[t >> 6] = __float_as_uint(ev_x);
        __syncthreads();
        if (t == 0) {
            float s = 0.0f;
            for (int w = 0; w < WGT / 64; w++) s += __uint_as_float(lds[w]);
            sum_ex_part[chunk] = s;
        }
    }
}

// ----------------- fused merge + suffix + final (one launch, manual grid barrier) -----------------
// 256 blocks x 256 threads; block b owns buckets [b*256, b*256+256).
__global__ __launch_bounds__(256) void merge_suffix_final_kernel(
        const v4u* __restrict__ hist4, double* __restrict__ chunk_sum,
        const float* __restrict__ sum_ex_part, unsigned int* __restrict__ ctrl,
        float* __restrict__ out) {
    const int t = threadIdx.x, b = blockIdx.x;
    const int tg = t >> 6, lane = t & 63;

    // phase 1: reduce 256 wg-slabs. wave tg handles wgs [tg*64, tg*64+64),
    // reading v4u (16 B/lane, 1 KB/wave/instruction).
    unsigned long long s[4] = {0ull, 0ull, 0ull, 0ull};
    unsigned int c[4] = {0u, 0u, 0u, 0u};
    const v4u* base = hist4 + (size_t)(tg * 64) * (NBUCKETS / 4) + (size_t)b * 64 + lane;
#pragma unroll 4
    for (int w = 0; w < 64; w++) {
        v4u h = base[(size_t)w * (NBUCKETS / 4)];
#pragma unroll
        for (int q = 0; q < 4; q++) {
            s[q] += (unsigned long long)(h[q] & SUM_MASK);
            c[q] += h[q] >> 28;
        }
    }
    __shared__ unsigned long long lsum[4][64][4];
    __shared__ unsigned int lcnt[4][64][4];
#pragma unroll
    for (int q = 0; q < 4; q++) { lsum[tg][lane][q] = s[q]; lcnt[tg][lane][q] = c[q]; }
    __syncthreads();

    // bucket b*256 + t  <->  (lane2 = t>>2, comp = t&3)
    unsigned long long Ssum = lsum[0][t >> 2][t & 3] + lsum[1][t >> 2][t & 3] +
                              lsum[2][t >> 2][t & 3] + lsum[3][t >> 2][t & 3];
    unsigned int M = lcnt[0][t >> 2][t & 3] + lcnt[1][t >> 2][t & 3] +
                     lcnt[2][t >> 2][t & 3] + lcnt[3][t >> 2][t & 3];
    double sv = (double)Ssum * INV_SCALE;

    __shared__ double red[256];
    __shared__ double sfx[256];
    __shared__ unsigned int ured[256];
    __shared__ int lastblk;

    // chunk total -> publish -> grid barrier (device-scope, cross-XCD safe)
    red[t] = sv;
    __syncthreads();
    for (int st = 128; st > 0; st >>= 1) {
        if (t < st) red[t] += red[t + st];
        __syncthreads();
    }
    if (t == 0) {
        __hip_atomic_store(&chunk_sum[b], red[0], __ATOMIC_RELEASE,
                           __HIP_MEMORY_SCOPE_AGENT);
        __hip_atomic_fetch_add(&ctrl[0], 1u, __ATOMIC_ACQ_REL,
                               __HIP_MEMORY_SCOPE_AGENT);
        while (__hip_atomic_load(&ctrl[0], __ATOMIC_ACQUIRE,
                                 __HIP_MEMORY_SCOPE_AGENT) < (unsigned)gridDim.x)
            __builtin_amdgcn_s_sleep(8);
    }
    __syncthreads();

    // phase 2: cross-chunk offset (sum of chunk_sum[c] for c > b)
    double cst = __hip_atomic_load(&chunk_sum[t], __ATOMIC_RELAXED,
                                   __HIP_MEMORY_SCOPE_AGENT);
    red[t] = (t > b) ? cst : 0.0;
    __syncthreads();
    for (int st = 128; st > 0; st >>= 1) {
        if (t < st) red[t] += red[t + st];
        __syncthreads();
    }
    double offset = red[0];
    __syncthreads();

    // inclusive suffix scan within chunk
    sfx[t] = sv;
    __syncthreads();
    for (int st = 1; st < 256; st <<= 1) {
        double add = (t + st < 256) ? sfx[t + st] : 0.0;
        __syncthreads();
        sfx[t] += add;
        __syncthreads();
    }
    double denom = offset + sfx[t] + EPS;
    double nll = (M != 0u) ? (double)M * log(denom) : 0.0;

    // block reduce nll + event count, accumulate device-wide, last block finalizes
    red[t] = nll;
    ured[t] = M;
    __syncthreads();
    for (int st = 128; st > 0; st >>= 1) {
        if (t < st) { red[t] += red[t + st]; ured[t] += ured[t + st]; }
        __syncthreads();
    }
    if (t == 0) {
        atomicAdd((double*)ctrl + 1, red[0]);
        atomicAdd(&ctrl[4], ured[0]);
        __threadfence();
        unsigned int old = __hip_atomic_fetch_add(&ctrl[1], 1u, __ATOMIC_ACQ_REL,
                                                  __HIP_MEMORY_SCOPE_AGENT);
        lastblk = (old == (unsigned)gridDim.x - 1) ? 1 : 0;
    }
    __syncthreads();
    if (lastblk) {
        red[t] = (double)sum_ex_part[t];
        __syncthreads();
        for (int st = 128; st > 0; st >>= 1) {
            if (t < st) red[t] += red[t + st];
            __syncthreads();
        }
        if (t == 0) {
            double nllT = __hip_atomic_load((double*)ctrl + 1, __ATOMIC_RELAXED,
                                            __HIP_MEMORY_SCOPE_AGENT);
            unsigned int nev = __hip_atomic_load(&ctrl[4], __ATOMIC_RELAXED,
                                                 __HIP_MEMORY_SCOPE_AGENT);
            out[0] = (float)((nllT - red[0]) / ((double)nev + EPS));
        }
    }
}

// ------------------------- old (fallback) path kernels -------------------------
__global__ void zero_ws_kernel(unsigned long long* __restrict__ rep, int n) {
    int i = blockIdx.x * blockDim.x + threadIdx.x;
    if (i < n) rep[i] = 0ull;
}

__global__ __launch_bounds__(256) void scatter_atomic_kernel(
        const v4f* __restrict__ x4, const v4i* __restrict__ e4,
        const v4i* __restrict__ t4,
        unsigned long long* __restrict__ rep, float* __restrict__ sum_ex_part,
        int n4, const float* __restrict__ x_s, const int* __restrict__ e_s,
        const int* __restrict__ t_s, int tail_base, int tail_cnt) {
    int i = blockIdx.x * blockDim.x + threadIdx.x;
    unsigned long long* R = rep + (size_t)xcd_id() * NBUCKETS;
    float ev_x = 0.0f;
    if (i < n4) {
        v4f x = __builtin_nontemporal_load(&x4[i]);
        v4i e = __builtin_nontemporal_load(&e4[i]);
        v4i t = __builtin_nontemporal_load(&t4[i]);
#pragma unroll
        for (int k = 0; k < 4; k++) {
            float xv = x[k];
            unsigned int v = (unsigned int)t[k] & 0xFFFFu;
            unsigned long long pk =
                ((unsigned long long)(e[k] != 0) << 48) +
                (unsigned long long)(expf(xv) * OSCALE_F + 0.5f);
            __hip_atomic_fetch_add(&R[v], pk, __ATOMIC_RELAXED,
                                   __HIP_MEMORY_SCOPE_WORKGROUP);
            if (e[k]) ev_x += xv;
        }
    }
    if (i < tail_cnt) {
        int idx = tail_base + i;
        float xv = x_s[idx];
        unsigned int v = (unsigned int)t_s[idx] & 0xFFFFu;
        unsigned long long pk =
            ((unsigned long long)(e_s[idx] != 0) << 48) +
            (unsigned long long)(expf(xv) * OSCALE_F + 0.5f);
        __hip_atomic_fetch_add(&R[v], pk, __ATOMIC_RELAXED,
                               __HIP_MEMORY_SCOPE_WORKGROUP);
        if (e_s[idx]) ev_x += xv;
    }
    __shared__ float sred[256];
    sred[threadIdx.x] = ev_x;
    __syncthreads();
    for (int s = 128; s > 0; s >>= 1) {
        if ((int)threadIdx.x < s) sred[threadIdx.x] += sred[threadIdx.x + s];
        __syncthreads();
    }
    if (threadIdx.x == 0) sum_ex_part[blockIdx.x] = sred[0];
}

__global__ __launch_bounds__(256) void reduce_kernel(
        const unsigned long long* __restrict__ rep, double* __restrict__ Sd,
        unsigned int* __restrict__ m, double* __restrict__ chunk_sum) {
    int t = threadIdx.x;
    int i = blockIdx.x * 256 + t;
    unsigned long long acc = 0ull;
#pragma unroll
    for (int r = 0; r < NREP; r++) acc += rep[(size_t)r * NBUCKETS + i];
    double sv = (double)(acc & LOW48) * OINV_SCALE;
    unsigned int mv = (unsigned int)(acc >> 48);
    Sd[i] = sv;
    m[i] = mv;
    __shared__ double red[256];
    red[t] = sv;
    __syncthreads();
    for (int s = 128; s > 0; s >>= 1) {
        if (t < s) red[t] += red[t + s];
        __syncthreads();
    }
    if (t == 0) chunk_sum[blockIdx.x] = red[0];
}

__global__ __launch_bounds__(256) void suffix_kernel(
        const double* __restrict__ Sd, const unsigned int* __restrict__ m,
        const double* __restrict__ chunk_sum, double* __restrict__ nll_part,
        unsigned int* __restrict__ nev_part) {
    __shared__ double cs[256];
    __shared__ double sfx[256];
    __shared__ unsigned int ured[256];
    const int t = threadIdx.x;
    const int b = blockIdx.x;

    cs[t] = (t > b) ? chunk_sum[t] : 0.0;
    __syncthreads();
    for (int s = 128; s > 0; s >>= 1) {
        if (t < s) cs[t] += cs[t + s];
        __syncthreads();
    }
    double offset = cs[0];
    __syncthreads();

    int i = b * 256 + t;
    double sv = Sd[i];
    unsigned int mv = m[i];

    sfx[t] = sv;
    __syncthreads();
    for (int s = 1; s < 256; s <<= 1) {
        double add = (t + s < 256) ? sfx[t + s] : 0.0;
        __syncthreads();
        sfx[t] += add;
        __syncthreads();
    }

    double denom = offset + sfx[t] + EPS;
    double nll = (mv != 0u) ? (double)mv * log(denom) : 0.0;

    cs[t] = nll;
    ured[t] = mv;
    __syncthreads();
    for (int s = 128; s > 0; s >>= 1) {
        if (t < s) { cs[t] += cs[t + s]; ured[t] += ured[t + s]; }
        __syncthreads();
    }
    if (t == 0) {
        nll_part[b] = cs[0];
        nev_part[b] = ured[0];
    }
}

__global__ __launch_bounds__(256) void final_kernel(
        const double* __restrict__ nll_part, const unsigned int* __restrict__ nev_part,
        const float* __restrict__ sum_ex_part, int n_sx, float* __restrict__ out) {
    __shared__ double rd[256];
    __shared__ double rs[256];
    __shared__ unsigned int ru[256];
    int t = threadIdx.x;
    double nll = nll_part[t];
    unsigned int ne = nev_part[t];
    double sx = 0.0;
    for (int i = t; i < n_sx; i += 256) sx += (double)sum_ex_part[i];
    rd[t] = nll;
    rs[t] = sx;
    ru[t] = ne;
    __syncthreads();
    for (int s = 128; s > 0; s >>= 1) {
        if (t < s) { rd[t] += rd[t + s]; rs[t] += rs[t + s]; ru[t] += ru[t + s]; }
        __syncthreads();
    }
    if (t == 0) {
        double total = rd[0] - rs[0];
        out[0] = (float)(total / ((double)ru[0] + EPS));
    }
}

extern "C" void kernel_launch(void* const* d_in, const int* in_sizes, int n_in,
                              void* d_out, int out_size, void* d_ws, size_t ws_size,
                              hipStream_t stream) {
    const float* logits = (const float*)d_in[0];
    const int* status = (const int*)d_in[1];
    const int* time = (const int*)d_in[2];
    const int N = in_sizes[0];

    char* ws = (char*)d_ws;
    int n4 = N / 4;
    int tail_base = n4 * 4;
    int tail_cnt = N - tail_base;

    if (ws_size >= (size_t)REQ_NEW && N <= NWG * WGT * RROUNDS * 4) {
        unsigned int* hist = (unsigned int*)(ws + OFF_HIST);
        double* chunk_sum = (double*)(ws + OFF_CS);
        float* sum_ex_part = (float*)(ws + OFF_SX);
        unsigned int* ctrl = (unsigned int*)(ws + OFF_CTRL);

        scatter_half_kernel<<<NWG * 2, WGT, 0, stream>>>(
            (const v4f*)logits, (const v4i*)status, (const v4i*)time,
            hist, sum_ex_part, ctrl, n4, logits, status, time, tail_base, tail_cnt);
        merge_suffix_final_kernel<<<256, 256, 0, stream>>>(
            (const v4u*)hist, chunk_sum, sum_ex_part, ctrl, (float*)d_out);
    } else {
        unsigned long long* rep = (unsigned long long*)(ws + O_REP);
        double* Sd = (double*)(ws + O_SD);
        unsigned int* m = (unsigned int*)(ws + O_M);
        double* chunk_sum = (double*)(ws + O_CS);
        double* nll_part = (double*)(ws + O_NLL);
        unsigned int* nev_part = (unsigned int*)(ws + O_NEV);
        float* sum_ex_part = (float*)(ws + O_SX);

        int nrep_total = NREP * NBUCKETS;
        zero_ws_kernel<<<(nrep_total + 255) / 256, 256, 0, stream>>>(rep, nrep_total);
        int blocks = (n4 + 255) / 256;
        if (blocks < 1) blocks = 1;
        scatter_atomic_kernel<<<blocks, 256, 0, stream>>>(
            (const v4f*)logits, (const v4i*)status, (const v4i*)time,
            rep, sum_ex_part, n4, logits, status, time, tail_base, tail_cnt);
        reduce_kernel<<<256, 256, 0, stream>>>(rep, Sd, m, chunk_sum);
        suffix_kernel<<<256, 256, 0, stream>>>(Sd, m, chunk_sum, nll_part, nev_part);
        final_kernel<<<1, 256, 0, stream>>>(nll_part, nev_part, sum_ex_part, blocks,
                                            (float*)d_out);
    }
}

// Round 8
// 175.801 us; speedup vs baseline: 6.2252x; 1.0704x over previous
//
#include <hip/hip_runtime.h>
#include <math.h>

#define NBUCKETS 65536
#define EPS 1e-12

typedef float v4f __attribute__((ext_vector_type(4)));
typedef int v4i __attribute__((ext_vector_type(4)));
typedef unsigned int v4u __attribute__((ext_vector_type(4)));

// ---------------- main path: 128 chunks x 2 halves = 256 wgs (1 per CU) ----------------
#define NCHUNK 128          // input chunks
#define WGT 1024
#define RROUNDS 16          // v4 loads per thread -> 64 items/thread/chunk
#define PBUCK 32768         // buckets per half (128 KB LDS -> 1 wg/CU)
#define SCALE_F 131072.0f   // 2^17 fixed point
#define INV_SCALE (1.0 / 131072.0)
#define SUM_MASK 0x0FFFFFFFu

// ws layout
#define OFF_HIST 0                                          // 128*65536*4 = 32 MB
#define OFF_CS   (NCHUNK * NBUCKETS * 4)                    // 33554432, 256 doubles
#define OFF_SX   (OFF_CS + 256 * 8)                         // 33556480, 128 floats
#define OFF_CTRL (OFF_SX + NCHUNK * 4)                      // 33556992, 64 B control
#define REQ_NEW  (OFF_CTRL + 64)
// ctrl: [0]=phase1 counter, [1]=phase2 counter, [2..3]=nll_total (double), [4]=nev_total

// old (fallback) ws layout
#define NREP 8
#define OSCALE_F 1073741824.0f
#define OINV_SCALE (1.0 / 1073741824.0)
#define LOW48 ((1ull << 48) - 1)
#define O_REP 0
#define O_SD (NREP * NBUCKETS * 8)
#define O_M (O_SD + NBUCKETS * 8)
#define O_CS (O_M + NBUCKETS * 4)
#define O_NLL (O_CS + 256 * 8)
#define O_NEV (O_NLL + 256 * 8)
#define O_SX (O_NEV + 256 * 4)
#define REQ_OLD (O_SX + 8192 * 4)

__device__ __forceinline__ unsigned int xcd_id() {
    unsigned int x;
    asm volatile("s_getreg_b32 %0, hwreg(HW_REG_XCC_ID)" : "=s"(x));
    return x & 7u;
}

// ------------- scatter: 256 wgs = (chunk, bucket-half); stream -> LDS atomics -> slab -------------
// NO per-item register stash: rounds 5/6 showed the allocator pins VGPR=64 and
// spills a 64-reg stash to scratch (1.5 GB fetch, 25x slowdown) regardless of
// __launch_bounds__ hints. Each wg streams its chunk and filters to its bucket
// half; the chunk's other-half twin wg runs concurrently on another CU, so the
// second read of each line hits L2/L3. ~52 VGPRs live -> spill-proof.
__global__ __launch_bounds__(WGT) void scatter_half_kernel(
        const v4f* __restrict__ x4, const v4i* __restrict__ e4,
        const v4i* __restrict__ t4, unsigned int* __restrict__ hist,
        float* __restrict__ sum_ex_part, unsigned int* __restrict__ ctrl, int n4,
        const float* __restrict__ x_s, const int* __restrict__ e_s,
        const int* __restrict__ t_s, int tail_base, int tail_cnt) {
    __shared__ unsigned int lds[PBUCK];
    const int t = threadIdx.x;
    const int wg = blockIdx.x;
    const int half = wg & 1;
    const int chunk = wg >> 1;

    // zero the control block for the fused tail kernel (kernel-boundary visibility)
    if (wg == 0 && t == 0) {
        ctrl[0] = 0u;
        ctrl[1] = 0u;
        ((double*)ctrl)[1] = 0.0;   // nll_total at bytes 8..15
        ctrl[4] = 0u;
    }

    // zero the LDS histogram
    v4u* lds4 = (v4u*)lds;
#pragma unroll
    for (int q = 0; q < PBUCK / 4 / WGT; q++)
        lds4[t + q * WGT] = (v4u){0u, 0u, 0u, 0u};
    __syncthreads();

    float ev_x = 0.0f;
    const unsigned int uh = (unsigned int)half;

#pragma unroll 1
    for (int r = 0; r < RROUNDS; r++) {
        int idx = (chunk * RROUNDS + r) * WGT + t;
        if (idx < n4) {
            v4f x = __builtin_nontemporal_load(&x4[idx]);
            v4i e = __builtin_nontemporal_load(&e4[idx]);
            v4i tm = __builtin_nontemporal_load(&t4[idx]);
#pragma unroll
            for (int k = 0; k < 4; k++) {
                float xv = x[k];
                unsigned int b = (unsigned int)tm[k] & 0xFFFFu;
                unsigned int ev = (e[k] != 0) ? 1u : 0u;
                if ((b >> 15) == uh) {
                    unsigned int pk = (ev << 28) +
                                      (unsigned int)(expf(xv) * SCALE_F + 0.5f);
                    atomicAdd(&lds[b & (PBUCK - 1)], pk);
                }
                if (half == 0 && ev) ev_x += xv;  // sum_ex counted once (half 0)
            }
        }
    }

    // N%4 tail: both halves of chunk 0 check it (each keeps matching buckets)
    if (chunk == 0 && t == 0 && tail_cnt > 0) {
        for (int i = 0; i < tail_cnt; i++) {
            int idx = tail_base + i;
            float xv = x_s[idx];
            unsigned int b = (unsigned int)t_s[idx] & 0xFFFFu;
            unsigned int ev = (e_s[idx] != 0) ? 1u : 0u;
            if ((b >> 15) == uh) {
                unsigned int pk = (ev << 28) +
                                  (unsigned int)(expf(xv) * SCALE_F + 0.5f);
                atomicAdd(&lds[b & (PBUCK - 1)], pk);
            }
            if (half == 0 && ev) ev_x += xv;
        }
    }
    __syncthreads();

    // coalesced write-out of this half's 32K-bucket slab
    v4u* hbase = (v4u*)(hist + (size_t)chunk * NBUCKETS + (size_t)half * PBUCK);
#pragma unroll
    for (int q = 0; q < PBUCK / 4 / WGT; q++) {
        v4u v = lds4[t + q * WGT];
        __builtin_nontemporal_store(v, &hbase[t + q * WGT]);
    }

    // sum_ex partial (half 0 only): wave reduce, then cross-wave via LDS
    if (half == 0) {
        __syncthreads();
#pragma unroll
        for (int off = 32; off > 0; off >>= 1) ev_x += __shfl_down(ev_x, off, 64);
        if ((t & 63) == 0) lds[t >> 6] = __float_as_uint(ev_x);
        __syncthreads();
        if (t == 0) {
            float s = 0.0f;
            for (int w = 0; w < WGT / 64; w++) s += __uint_as_float(lds[w]);
            sum_ex_part[chunk] = s;
        }
    }
}

// ----------------- fused merge + suffix + final (one launch, manual grid barrier) -----------------
// 256 blocks x 256 threads; block b owns buckets [b*256, b*256+256).
__global__ __launch_bounds__(256) void merge_suffix_final_kernel(
        const v4u* __restrict__ hist4, double* __restrict__ chunk_sum,
        const float* __restrict__ sum_ex_part, unsigned int* __restrict__ ctrl,
        float* __restrict__ out) {
    const int t = threadIdx.x, b = blockIdx.x;
    const int tg = t >> 6, lane = t & 63;

    // phase 1: reduce 128 chunk-slabs. wave tg handles slabs [tg*32, tg*32+32),
    // reading v4u (16 B/lane, 1 KB/wave/instruction).
    unsigned long long s[4] = {0ull, 0ull, 0ull, 0ull};
    unsigned int c[4] = {0u, 0u, 0u, 0u};
    const v4u* base = hist4 + (size_t)(tg * (NCHUNK / 4)) * (NBUCKETS / 4) +
                      (size_t)b * 64 + lane;
#pragma unroll 4
    for (int w = 0; w < NCHUNK / 4; w++) {
        v4u h = base[(size_t)w * (NBUCKETS / 4)];
#pragma unroll
        for (int q = 0; q < 4; q++) {
            s[q] += (unsigned long long)(h[q] & SUM_MASK);
            c[q] += h[q] >> 28;
        }
    }
    __shared__ unsigned long long lsum[4][64][4];
    __shared__ unsigned int lcnt[4][64][4];
#pragma unroll
    for (int q = 0; q < 4; q++) { lsum[tg][lane][q] = s[q]; lcnt[tg][lane][q] = c[q]; }
    __syncthreads();

    // bucket b*256 + t  <->  (lane2 = t>>2, comp = t&3)
    unsigned long long Ssum = lsum[0][t >> 2][t & 3] + lsum[1][t >> 2][t & 3] +
                              lsum[2][t >> 2][t & 3] + lsum[3][t >> 2][t & 3];
    unsigned int M = lcnt[0][t >> 2][t & 3] + lcnt[1][t >> 2][t & 3] +
                     lcnt[2][t >> 2][t & 3] + lcnt[3][t >> 2][t & 3];
    double sv = (double)Ssum * INV_SCALE;

    __shared__ double red[256];
    __shared__ double sfx[256];
    __shared__ unsigned int ured[256];
    __shared__ int lastblk;

    // chunk total -> publish -> grid barrier (device-scope, cross-XCD safe)
    red[t] = sv;
    __syncthreads();
    for (int st = 128; st > 0; st >>= 1) {
        if (t < st) red[t] += red[t + st];
        __syncthreads();
    }
    if (t == 0) {
        __hip_atomic_store(&chunk_sum[b], red[0], __ATOMIC_RELEASE,
                           __HIP_MEMORY_SCOPE_AGENT);
        __hip_atomic_fetch_add(&ctrl[0], 1u, __ATOMIC_ACQ_REL,
                               __HIP_MEMORY_SCOPE_AGENT);
        while (__hip_atomic_load(&ctrl[0], __ATOMIC_ACQUIRE,
                                 __HIP_MEMORY_SCOPE_AGENT) < (unsigned)gridDim.x)
            __builtin_amdgcn_s_sleep(8);
    }
    __syncthreads();

    // phase 2: cross-chunk offset (sum of chunk_sum[c] for c > b)
    double cst = __hip_atomic_load(&chunk_sum[t], __ATOMIC_RELAXED,
                                   __HIP_MEMORY_SCOPE_AGENT);
    red[t] = (t > b) ? cst : 0.0;
    __syncthreads();
    for (int st = 128; st > 0; st >>= 1) {
        if (t < st) red[t] += red[t + st];
        __syncthreads();
    }
    double offset = red[0];
    __syncthreads();

    // inclusive suffix scan within chunk
    sfx[t] = sv;
    __syncthreads();
    for (int st = 1; st < 256; st <<= 1) {
        double add = (t + st < 256) ? sfx[t + st] : 0.0;
        __syncthreads();
        sfx[t] += add;
        __syncthreads();
    }
    double denom = offset + sfx[t] + EPS;
    double nll = (M != 0u) ? (double)M * log(denom) : 0.0;

    // block reduce nll + event count, accumulate device-wide, last block finalizes
    red[t] = nll;
    ured[t] = M;
    __syncthreads();
    for (int st = 128; st > 0; st >>= 1) {
        if (t < st) { red[t] += red[t + st]; ured[t] += ured[t + st]; }
        __syncthreads();
    }
    if (t == 0) {
        atomicAdd((double*)ctrl + 1, red[0]);
        atomicAdd(&ctrl[4], ured[0]);
        __threadfence();
        unsigned int old = __hip_atomic_fetch_add(&ctrl[1], 1u, __ATOMIC_ACQ_REL,
                                                  __HIP_MEMORY_SCOPE_AGENT);
        lastblk = (old == (unsigned)gridDim.x - 1) ? 1 : 0;
    }
    __syncthreads();
    if (lastblk) {
        red[t] = (t < NCHUNK) ? (double)sum_ex_part[t] : 0.0;
        __syncthreads();
        for (int st = 128; st > 0; st >>= 1) {
            if (t < st) red[t] += red[t + st];
            __syncthreads();
        }
        if (t == 0) {
            double nllT = __hip_atomic_load((double*)ctrl + 1, __ATOMIC_RELAXED,
                                            __HIP_MEMORY_SCOPE_AGENT);
            unsigned int nev = __hip_atomic_load(&ctrl[4], __ATOMIC_RELAXED,
                                                 __HIP_MEMORY_SCOPE_AGENT);
            out[0] = (float)((nllT - red[0]) / ((double)nev + EPS));
        }
    }
}

// ------------------------- old (fallback) path kernels -------------------------
__global__ void zero_ws_kernel(unsigned long long* __restrict__ rep, int n) {
    int i = blockIdx.x * blockDim.x + threadIdx.x;
    if (i < n) rep[i] = 0ull;
}

__global__ __launch_bounds__(256) void scatter_atomic_kernel(
        const v4f* __restrict__ x4, const v4i* __restrict__ e4,
        const v4i* __restrict__ t4,
        unsigned long long* __restrict__ rep, float* __restrict__ sum_ex_part,
        int n4, const float* __restrict__ x_s, const int* __restrict__ e_s,
        const int* __restrict__ t_s, int tail_base, int tail_cnt) {
    int i = blockIdx.x * blockDim.x + threadIdx.x;
    unsigned long long* R = rep + (size_t)xcd_id() * NBUCKETS;
    float ev_x = 0.0f;
    if (i < n4) {
        v4f x = __builtin_nontemporal_load(&x4[i]);
        v4i e = __builtin_nontemporal_load(&e4[i]);
        v4i t = __builtin_nontemporal_load(&t4[i]);
#pragma unroll
        for (int k = 0; k < 4; k++) {
            float xv = x[k];
            unsigned int v = (unsigned int)t[k] & 0xFFFFu;
            unsigned long long pk =
                ((unsigned long long)(e[k] != 0) << 48) +
                (unsigned long long)(expf(xv) * OSCALE_F + 0.5f);
            __hip_atomic_fetch_add(&R[v], pk, __ATOMIC_RELAXED,
                                   __HIP_MEMORY_SCOPE_WORKGROUP);
            if (e[k]) ev_x += xv;
        }
    }
    if (i < tail_cnt) {
        int idx = tail_base + i;
        float xv = x_s[idx];
        unsigned int v = (unsigned int)t_s[idx] & 0xFFFFu;
        unsigned long long pk =
            ((unsigned long long)(e_s[idx] != 0) << 48) +
            (unsigned long long)(expf(xv) * OSCALE_F + 0.5f);
        __hip_atomic_fetch_add(&R[v], pk, __ATOMIC_RELAXED,
                               __HIP_MEMORY_SCOPE_WORKGROUP);
        if (e_s[idx]) ev_x += xv;
    }
    __shared__ float sred[256];
    sred[threadIdx.x] = ev_x;
    __syncthreads();
    for (int s = 128; s > 0; s >>= 1) {
        if ((int)threadIdx.x < s) sred[threadIdx.x] += sred[threadIdx.x + s];
        __syncthreads();
    }
    if (threadIdx.x == 0) sum_ex_part[blockIdx.x] = sred[0];
}

__global__ __launch_bounds__(256) void reduce_kernel(
        const unsigned long long* __restrict__ rep, double* __restrict__ Sd,
        unsigned int* __restrict__ m, double* __restrict__ chunk_sum) {
    int t = threadIdx.x;
    int i = blockIdx.x * 256 + t;
    unsigned long long acc = 0ull;
#pragma unroll
    for (int r = 0; r < NREP; r++) acc += rep[(size_t)r * NBUCKETS + i];
    double sv = (double)(acc & LOW48) * OINV_SCALE;
    unsigned int mv = (unsigned int)(acc >> 48);
    Sd[i] = sv;
    m[i] = mv;
    __shared__ double red[256];
    red[t] = sv;
    __syncthreads();
    for (int s = 128; s > 0; s >>= 1) {
        if (t < s) red[t] += red[t + s];
        __syncthreads();
    }
    if (t == 0) chunk_sum[blockIdx.x] = red[0];
}

__global__ __launch_bounds__(256) void suffix_kernel(
        const double* __restrict__ Sd, const unsigned int* __restrict__ m,
        const double* __restrict__ chunk_sum, double* __restrict__ nll_part,
        unsigned int* __restrict__ nev_part) {
    __shared__ double cs[256];
    __shared__ double sfx[256];
    __shared__ unsigned int ured[256];
    const int t = threadIdx.x;
    const int b = blockIdx.x;

    cs[t] = (t > b) ? chunk_sum[t] : 0.0;
    __syncthreads();
    for (int s = 128; s > 0; s >>= 1) {
        if (t < s) cs[t] += cs[t + s];
        __syncthreads();
    }
    double offset = cs[0];
    __syncthreads();

    int i = b * 256 + t;
    double sv = Sd[i];
    unsigned int mv = m[i];

    sfx[t] = sv;
    __syncthreads();
    for (int s = 1; s < 256; s <<= 1) {
        double add = (t + s < 256) ? sfx[t + s] : 0.0;
        __syncthreads();
        sfx[t] += add;
        __syncthreads();
    }

    double denom = offset + sfx[t] + EPS;
    double nll = (mv != 0u) ? (double)mv * log(denom) : 0.0;

    cs[t] = nll;
    ured[t] = mv;
    __syncthreads();
    for (int s = 128; s > 0; s >>= 1) {
        if (t < s) { cs[t] += cs[t + s]; ured[t] += ured[t + s]; }
        __syncthreads();
    }
    if (t == 0) {
        nll_part[b] = cs[0];
        nev_part[b] = ured[0];
    }
}

__global__ __launch_bounds__(256) void final_kernel(
        const double* __restrict__ nll_part, const unsigned int* __restrict__ nev_part,
        const float* __restrict__ sum_ex_part, int n_sx, float* __restrict__ out) {
    __shared__ double rd[256];
    __shared__ double rs[256];
    __shared__ unsigned int ru[256];
    int t = threadIdx.x;
    double nll = nll_part[t];
    unsigned int ne = nev_part[t];
    double sx = 0.0;
    for (int i = t; i < n_sx; i += 256) sx += (double)sum_ex_part[i];
    rd[t] = nll;
    rs[t] = sx;
    ru[t] = ne;
    __syncthreads();
    for (int s = 128; s > 0; s >>= 1) {
        if (t < s) { rd[t] += rd[t + s]; rs[t] += rs[t + s]; ru[t] += ru[t + s]; }
        __syncthreads();
    }
    if (t == 0) {
        double total = rd[0] - rs[0];
        out[0] = (float)(total / ((double)ru[0] + EPS));
    }
}

extern "C" void kernel_launch(void* const* d_in, const int* in_sizes, int n_in,
                              void* d_out, int out_size, void* d_ws, size_t ws_size,
                              hipStream_t stream) {
    const float* logits = (const float*)d_in[0];
    const int* status = (const int*)d_in[1];
    const int* time = (const int*)d_in[2];
    const int N = in_sizes[0];

    char* ws = (char*)d_ws;
    int n4 = N / 4;
    int tail_base = n4 * 4;
    int tail_cnt = N - tail_base;

    if (ws_size >= (size_t)REQ_NEW && N <= NCHUNK * WGT * RROUNDS * 4) {
        unsigned int* hist = (unsigned int*)(ws + OFF_HIST);
        double* chunk_sum = (double*)(ws + OFF_CS);
        float* sum_ex_part = (float*)(ws + OFF_SX);
        unsigned int* ctrl = (unsigned int*)(ws + OFF_CTRL);

        scatter_half_kernel<<<NCHUNK * 2, WGT, 0, stream>>>(
            (const v4f*)logits, (const v4i*)status, (const v4i*)time,
            hist, sum_ex_part, ctrl, n4, logits, status, time, tail_base, tail_cnt);
        merge_suffix_final_kernel<<<256, 256, 0, stream>>>(
            (const v4u*)hist, chunk_sum, sum_ex_part, ctrl, (float*)d_out);
    } else {
        unsigned long long* rep = (unsigned long long*)(ws + O_REP);
        double* Sd = (double*)(ws + O_SD);
        unsigned int* m = (unsigned int*)(ws + O_M);
        double* chunk_sum = (double*)(ws + O_CS);
        double* nll_part = (double*)(ws + O_NLL);
        unsigned int* nev_part = (unsigned int*)(ws + O_NEV);
        float* sum_ex_part = (float*)(ws + O_SX);

        int nrep_total = NREP * NBUCKETS;
        zero_ws_kernel<<<(nrep_total + 255) / 256, 256, 0, stream>>>(rep, nrep_total);
        int blocks = (n4 + 255) / 256;
        if (blocks < 1) blocks = 1;
        scatter_atomic_kernel<<<blocks, 256, 0, stream>>>(
            (const v4f*)logits, (const v4i*)status, (const v4i*)time,
            rep, sum_ex_part, n4, logits, status, time, tail_base, tail_cnt);
        reduce_kernel<<<256, 256, 0, stream>>>(rep, Sd, m, chunk_sum);
        suffix_kernel<<<256, 256, 0, stream>>>(Sd, m, chunk_sum, nll_part, nev_part);
        final_kernel<<<1, 256, 0, stream>>>(nll_part, nev_part, sum_ex_part, blocks,
                                            (float*)d_out);
    }
}

// Round 9
// 154.211 us; speedup vs baseline: 7.0967x; 1.1400x over previous
//
#include <hip/hip_runtime.h>
#include <math.h>

#define NBUCKETS 65536
#define EPS 1e-12

typedef float v4f __attribute__((ext_vector_type(4)));
typedef int v4i __attribute__((ext_vector_type(4)));
typedef unsigned int v4u __attribute__((ext_vector_type(4)));

// ---------------- main path: 128 chunks x 2 halves = 256 wgs (1 per CU) ----------------
#define NCHUNK 128          // input chunks
#define WGT 1024
#define RROUNDS 16          // v4 loads per thread -> 64 items/thread/chunk
#define PBUCK 32768         // buckets per half (128 KB LDS -> 1 wg/CU)
#define SCALE_F 131072.0f   // 2^17 fixed point
#define INV_SCALE (1.0 / 131072.0)
#define SUM_MASK 0x0FFFFFFFu

// ws layout
#define OFF_HIST 0                                          // 128*65536*4 = 32 MB
#define OFF_SD   (NCHUNK * NBUCKETS * 4)                    // 33554432, 64K doubles
#define OFF_M    (OFF_SD + NBUCKETS * 8)                    // 34078720, 64K u32
#define OFF_CS   (OFF_M + NBUCKETS * 4)                     // 34340864, 256 doubles
#define OFF_NLL  (OFF_CS + 256 * 8)                         // 34342912, 256 doubles
#define OFF_NEV  (OFF_NLL + 256 * 8)                        // 34344960, 256 u32
#define OFF_SX   (OFF_NEV + 256 * 4)                        // 34345984, 128 floats
#define REQ_NEW  (OFF_SX + NCHUNK * 4)

// old (fallback) ws layout
#define NREP 8
#define OSCALE_F 1073741824.0f
#define OINV_SCALE (1.0 / 1073741824.0)
#define LOW48 ((1ull << 48) - 1)
#define O_REP 0
#define O_SD (NREP * NBUCKETS * 8)
#define O_M (O_SD + NBUCKETS * 8)
#define O_CS (O_M + NBUCKETS * 4)
#define O_NLL (O_CS + 256 * 8)
#define O_NEV (O_NLL + 256 * 8)
#define O_SX (O_NEV + 256 * 4)
#define REQ_OLD (O_SX + 8192 * 4)

__device__ __forceinline__ unsigned int xcd_id() {
    unsigned int x;
    asm volatile("s_getreg_b32 %0, hwreg(HW_REG_XCC_ID)" : "=s"(x));
    return x & 7u;
}

// ------------- scatter: 256 wgs = (chunk, bucket-half); stream -> LDS atomics -> slab -------------
// NO per-item register stash: rounds 5/6 showed the allocator pins VGPR=64 and
// spills a 64-reg stash to scratch (1.5 GB fetch, 25x slowdown) regardless of
// __launch_bounds__ hints. Each wg streams its chunk and filters to its bucket
// half; the chunk's other-half twin wg runs concurrently on another CU, so the
// second read is Infinity-Cache-resident (R8: FETCH == one read of the input).
__global__ __launch_bounds__(WGT) void scatter_half_kernel(
        const v4f* __restrict__ x4, const v4i* __restrict__ e4,
        const v4i* __restrict__ t4, unsigned int* __restrict__ hist,
        float* __restrict__ sum_ex_part, int n4,
        const float* __restrict__ x_s, const int* __restrict__ e_s,
        const int* __restrict__ t_s, int tail_base, int tail_cnt) {
    __shared__ unsigned int lds[PBUCK];
    const int t = threadIdx.x;
    const int wg = blockIdx.x;
    const int half = wg & 1;
    const int chunk = wg >> 1;

    // zero the LDS histogram
    v4u* lds4 = (v4u*)lds;
#pragma unroll
    for (int q = 0; q < PBUCK / 4 / WGT; q++)
        lds4[t + q * WGT] = (v4u){0u, 0u, 0u, 0u};
    __syncthreads();

    float ev_x = 0.0f;
    const unsigned int uh = (unsigned int)half;

#pragma unroll 1
    for (int r = 0; r < RROUNDS; r++) {
        int idx = (chunk * RROUNDS + r) * WGT + t;
        if (idx < n4) {
            v4f x = __builtin_nontemporal_load(&x4[idx]);
            v4i e = __builtin_nontemporal_load(&e4[idx]);
            v4i tm = __builtin_nontemporal_load(&t4[idx]);
#pragma unroll
            for (int k = 0; k < 4; k++) {
                float xv = x[k];
                unsigned int b = (unsigned int)tm[k] & 0xFFFFu;
                unsigned int ev = (e[k] != 0) ? 1u : 0u;
                if ((b >> 15) == uh) {
                    unsigned int pk = (ev << 28) +
                                      (unsigned int)(expf(xv) * SCALE_F + 0.5f);
                    atomicAdd(&lds[b & (PBUCK - 1)], pk);
                }
                if (half == 0 && ev) ev_x += xv;  // sum_ex counted once (half 0)
            }
        }
    }

    // N%4 tail: both halves of chunk 0 check it (each keeps matching buckets)
    if (chunk == 0 && t == 0 && tail_cnt > 0) {
        for (int i = 0; i < tail_cnt; i++) {
            int idx = tail_base + i;
            float xv = x_s[idx];
            unsigned int b = (unsigned int)t_s[idx] & 0xFFFFu;
            unsigned int ev = (e_s[idx] != 0) ? 1u : 0u;
            if ((b >> 15) == uh) {
                unsigned int pk = (ev << 28) +
                                  (unsigned int)(expf(xv) * SCALE_F + 0.5f);
                atomicAdd(&lds[b & (PBUCK - 1)], pk);
            }
            if (half == 0 && ev) ev_x += xv;
        }
    }
    __syncthreads();

    // coalesced write-out of this half's 32K-bucket slab
    v4u* hbase = (v4u*)(hist + (size_t)chunk * NBUCKETS + (size_t)half * PBUCK);
#pragma unroll
    for (int q = 0; q < PBUCK / 4 / WGT; q++) {
        v4u v = lds4[t + q * WGT];
        __builtin_nontemporal_store(v, &hbase[t + q * WGT]);
    }

    // sum_ex partial (half 0 only): wave reduce, then cross-wave via LDS
    if (half == 0) {
        __syncthreads();
#pragma unroll
        for (int off = 32; off > 0; off >>= 1) ev_x += __shfl_down(ev_x, off, 64);
        if ((t & 63) == 0) lds[t >> 6] = __float_as_uint(ev_x);
        __syncthreads();
        if (t == 0) {
            float s = 0.0f;
            for (int w = 0; w < WGT / 64; w++) s += __uint_as_float(lds[w]);
            sum_ex_part[chunk] = s;
        }
    }
}

// ------------- split tail (R4-proven structure; NO grid barrier — R8's fused
// spin-barrier version ran ~42 us vs ~15 for the split) -------------
// merge: 256 blocks x 256 threads; block b owns buckets [b*256, b*256+256).
// wave tg reduces slabs [tg*32, tg*32+32) with v4u reads (1 KB/wave/instr).
__global__ __launch_bounds__(256) void merge_chunk_kernel(
        const v4u* __restrict__ hist4, double* __restrict__ Sd,
        unsigned int* __restrict__ m, double* __restrict__ chunk_sum) {
    const int t = threadIdx.x, b = blockIdx.x;
    const int tg = t >> 6, lane = t & 63;

    unsigned long long s[4] = {0ull, 0ull, 0ull, 0ull};
    unsigned int c[4] = {0u, 0u, 0u, 0u};
    const v4u* base = hist4 + (size_t)(tg * (NCHUNK / 4)) * (NBUCKETS / 4) +
                      (size_t)b * 64 + lane;
#pragma unroll 4
    for (int w = 0; w < NCHUNK / 4; w++) {
        v4u h = base[(size_t)w * (NBUCKETS / 4)];
#pragma unroll
        for (int q = 0; q < 4; q++) {
            s[q] += (unsigned long long)(h[q] & SUM_MASK);
            c[q] += h[q] >> 28;
        }
    }
    __shared__ unsigned long long lsum[4][64][4];
    __shared__ unsigned int lcnt[4][64][4];
#pragma unroll
    for (int q = 0; q < 4; q++) { lsum[tg][lane][q] = s[q]; lcnt[tg][lane][q] = c[q]; }
    __syncthreads();

    // bucket b*256 + t  <->  (lane2 = t>>2, comp = t&3)  [mapping verified: absmax 0 in R8]
    unsigned long long Ssum = lsum[0][t >> 2][t & 3] + lsum[1][t >> 2][t & 3] +
                              lsum[2][t >> 2][t & 3] + lsum[3][t >> 2][t & 3];
    unsigned int M = lcnt[0][t >> 2][t & 3] + lcnt[1][t >> 2][t & 3] +
                     lcnt[2][t >> 2][t & 3] + lcnt[3][t >> 2][t & 3];
    double sv = (double)Ssum * INV_SCALE;
    Sd[b * 256 + t] = sv;
    m[b * 256 + t] = M;

    __shared__ double red[256];
    red[t] = sv;
    __syncthreads();
    for (int st = 128; st > 0; st >>= 1) {
        if (t < st) red[t] += red[t + st];
        __syncthreads();
    }
    if (t == 0) chunk_sum[b] = red[0];
}

__global__ __launch_bounds__(256) void suffix_kernel(
        const double* __restrict__ Sd, const unsigned int* __restrict__ m,
        const double* __restrict__ chunk_sum, double* __restrict__ nll_part,
        unsigned int* __restrict__ nev_part) {
    __shared__ double cs[256];
    __shared__ double sfx[256];
    __shared__ unsigned int ured[256];
    const int t = threadIdx.x;
    const int b = blockIdx.x;

    cs[t] = (t > b) ? chunk_sum[t] : 0.0;
    __syncthreads();
    for (int s = 128; s > 0; s >>= 1) {
        if (t < s) cs[t] += cs[t + s];
        __syncthreads();
    }
    double offset = cs[0];
    __syncthreads();

    int i = b * 256 + t;
    double sv = Sd[i];
    unsigned int mv = m[i];

    sfx[t] = sv;
    __syncthreads();
    for (int s = 1; s < 256; s <<= 1) {
        double add = (t + s < 256) ? sfx[t + s] : 0.0;
        __syncthreads();
        sfx[t] += add;
        __syncthreads();
    }

    double denom = offset + sfx[t] + EPS;
    double nll = (mv != 0u) ? (double)mv * log(denom) : 0.0;

    cs[t] = nll;
    ured[t] = mv;
    __syncthreads();
    for (int s = 128; s > 0; s >>= 1) {
        if (t < s) { cs[t] += cs[t + s]; ured[t] += ured[t + s]; }
        __syncthreads();
    }
    if (t == 0) {
        nll_part[b] = cs[0];
        nev_part[b] = ured[0];
    }
}

__global__ __launch_bounds__(256) void final_kernel(
        const double* __restrict__ nll_part, const unsigned int* __restrict__ nev_part,
        const float* __restrict__ sum_ex_part, int n_sx, float* __restrict__ out) {
    __shared__ double rd[256];
    __shared__ double rs[256];
    __shared__ unsigned int ru[256];
    int t = threadIdx.x;
    double nll = nll_part[t];
    unsigned int ne = nev_part[t];
    double sx = 0.0;
    for (int i = t; i < n_sx; i += 256) sx += (double)sum_ex_part[i];
    rd[t] = nll;
    rs[t] = sx;
    ru[t] = ne;
    __syncthreads();
    for (int s = 128; s > 0; s >>= 1) {
        if (t < s) { rd[t] += rd[t + s]; rs[t] += rs[t + s]; ru[t] += ru[t + s]; }
        __syncthreads();
    }
    if (t == 0) {
        double total = rd[0] - rs[0];
        out[0] = (float)(total / ((double)ru[0] + EPS));
    }
}

// ------------------------- old (fallback) path kernels -------------------------
__global__ void zero_ws_kernel(unsigned long long* __restrict__ rep, int n) {
    int i = blockIdx.x * blockDim.x + threadIdx.x;
    if (i < n) rep[i] = 0ull;
}

__global__ __launch_bounds__(256) void scatter_atomic_kernel(
        const v4f* __restrict__ x4, const v4i* __restrict__ e4,
        const v4i* __restrict__ t4,
        unsigned long long* __restrict__ rep, float* __restrict__ sum_ex_part,
        int n4, const float* __restrict__ x_s, const int* __restrict__ e_s,
        const int* __restrict__ t_s, int tail_base, int tail_cnt) {
    int i = blockIdx.x * blockDim.x + threadIdx.x;
    unsigned long long* R = rep + (size_t)xcd_id() * NBUCKETS;
    float ev_x = 0.0f;
    if (i < n4) {
        v4f x = __builtin_nontemporal_load(&x4[i]);
        v4i e = __builtin_nontemporal_load(&e4[i]);
        v4i t = __builtin_nontemporal_load(&t4[i]);
#pragma unroll
        for (int k = 0; k < 4; k++) {
            float xv = x[k];
            unsigned int v = (unsigned int)t[k] & 0xFFFFu;
            unsigned long long pk =
                ((unsigned long long)(e[k] != 0) << 48) +
                (unsigned long long)(expf(xv) * OSCALE_F + 0.5f);
            __hip_atomic_fetch_add(&R[v], pk, __ATOMIC_RELAXED,
                                   __HIP_MEMORY_SCOPE_WORKGROUP);
            if (e[k]) ev_x += xv;
        }
    }
    if (i < tail_cnt) {
        int idx = tail_base + i;
        float xv = x_s[idx];
        unsigned int v = (unsigned int)t_s[idx] & 0xFFFFu;
        unsigned long long pk =
            ((unsigned long long)(e_s[idx] != 0) << 48) +
            (unsigned long long)(expf(xv) * OSCALE_F + 0.5f);
        __hip_atomic_fetch_add(&R[v], pk, __ATOMIC_RELAXED,
                               __HIP_MEMORY_SCOPE_WORKGROUP);
        if (e_s[idx]) ev_x += xv;
    }
    __shared__ float sred[256];
    sred[threadIdx.x] = ev_x;
    __syncthreads();
    for (int s = 128; s > 0; s >>= 1) {
        if ((int)threadIdx.x < s) sred[threadIdx.x] += sred[threadIdx.x + s];
        __syncthreads();
    }
    if (threadIdx.x == 0) sum_ex_part[blockIdx.x] = sred[0];
}

__global__ __launch_bounds__(256) void reduce_kernel(
        const unsigned long long* __restrict__ rep, double* __restrict__ Sd,
        unsigned int* __restrict__ m, double* __restrict__ chunk_sum) {
    int t = threadIdx.x;
    int i = blockIdx.x * 256 + t;
    unsigned long long acc = 0ull;
#pragma unroll
    for (int r = 0; r < NREP; r++) acc += rep[(size_t)r * NBUCKETS + i];
    double sv = (double)(acc & LOW48) * OINV_SCALE;
    unsigned int mv = (unsigned int)(acc >> 48);
    Sd[i] = sv;
    m[i] = mv;
    __shared__ double red[256];
    red[t] = sv;
    __syncthreads();
    for (int s = 128; s > 0; s >>= 1) {
        if (t < s) red[t] += red[t + s];
        __syncthreads();
    }
    if (t == 0) chunk_sum[blockIdx.x] = red[0];
}

extern "C" void kernel_launch(void* const* d_in, const int* in_sizes, int n_in,
                              void* d_out, int out_size, void* d_ws, size_t ws_size,
                              hipStream_t stream) {
    const float* logits = (const float*)d_in[0];
    const int* status = (const int*)d_in[1];
    const int* time = (const int*)d_in[2];
    const int N = in_sizes[0];

    char* ws = (char*)d_ws;
    int n4 = N / 4;
    int tail_base = n4 * 4;
    int tail_cnt = N - tail_base;

    if (ws_size >= (size_t)REQ_NEW && N <= NCHUNK * WGT * RROUNDS * 4) {
        unsigned int* hist = (unsigned int*)(ws + OFF_HIST);
        double* Sd = (double*)(ws + OFF_SD);
        unsigned int* m = (unsigned int*)(ws + OFF_M);
        double* chunk_sum = (double*)(ws + OFF_CS);
        double* nll_part = (double*)(ws + OFF_NLL);
        unsigned int* nev_part = (unsigned int*)(ws + OFF_NEV);
        float* sum_ex_part = (float*)(ws + OFF_SX);

        scatter_half_kernel<<<NCHUNK * 2, WGT, 0, stream>>>(
            (const v4f*)logits, (const v4i*)status, (const v4i*)time,
            hist, sum_ex_part, n4, logits, status, time, tail_base, tail_cnt);
        merge_chunk_kernel<<<256, 256, 0, stream>>>((const v4u*)hist, Sd, m, chunk_sum);
        suffix_kernel<<<256, 256, 0, stream>>>(Sd, m, chunk_sum, nll_part, nev_part);
        final_kernel<<<1, 256, 0, stream>>>(nll_part, nev_part, sum_ex_part, NCHUNK,
                                            (float*)d_out);
    } else {
        unsigned long long* rep = (unsigned long long*)(ws + O_REP);
        double* Sd = (double*)(ws + O_SD);
        unsigned int* m = (unsigned int*)(ws + O_M);
        double* chunk_sum = (double*)(ws + O_CS);
        double* nll_part = (double*)(ws + O_NLL);
        unsigned int* nev_part = (unsigned int*)(ws + O_NEV);
        float* sum_ex_part = (float*)(ws + O_SX);

        int nrep_total = NREP * NBUCKETS;
        zero_ws_kernel<<<(nrep_total + 255) / 256, 256, 0, stream>>>(rep, nrep_total);
        int blocks = (n4 + 255) / 256;
        if (blocks < 1) blocks = 1;
        scatter_atomic_kernel<<<blocks, 256, 0, stream>>>(
            (const v4f*)logits, (const v4i*)status, (const v4i*)time,
            rep, sum_ex_part, n4, logits, status, time, tail_base, tail_cnt);
        reduce_kernel<<<256, 256, 0, stream>>>(rep, Sd, m, chunk_sum);
        suffix_kernel<<<256, 256, 0, stream>>>(Sd, m, chunk_sum, nll_part, nev_part);
        final_kernel<<<1, 256, 0, stream>>>(nll_part, nev_part, sum_ex_part, blocks,
                                            (float*)d_out);
    }
}